// Round 4
// baseline (395.326 us; speedup 1.0000x reference)
//
#include <hip/hip_runtime.h>
#include <math.h>
#include <float.h>

constexpr int B  = 4;
constexpr int N  = 3072;
constexpr int C  = 512;
constexpr int CL = 768;

typedef unsigned short u16;
typedef __attribute__((ext_vector_type(8))) short s16x8;
typedef __attribute__((ext_vector_type(4))) float f32x4;

// ---------------- JAX threefry2x32 (exact) ----------------
__device__ __forceinline__ unsigned rotl32(unsigned v, int d) { return (v << d) | (v >> (32 - d)); }

__device__ inline void threefry2x32(unsigned k0, unsigned k1, unsigned c0, unsigned c1,
                                    unsigned& o0, unsigned& o1) {
  unsigned ks0 = k0, ks1 = k1, ks2 = 0x1BD11BDAu ^ k0 ^ k1;
  unsigned x0 = c0 + ks0, x1 = c1 + ks1;
#define TF_RND(r) { x0 += x1; x1 = rotl32(x1, (r)); x1 ^= x0; }
  TF_RND(13) TF_RND(15) TF_RND(26) TF_RND(6)  x0 += ks1; x1 += ks2 + 1u;
  TF_RND(17) TF_RND(29) TF_RND(16) TF_RND(24) x0 += ks2; x1 += ks0 + 2u;
  TF_RND(13) TF_RND(15) TF_RND(26) TF_RND(6)  x0 += ks0; x1 += ks1 + 3u;
  TF_RND(17) TF_RND(29) TF_RND(16) TF_RND(24) x0 += ks1; x1 += ks2 + 4u;
  TF_RND(13) TF_RND(15) TF_RND(26) TF_RND(6)  x0 += ks2; x1 += ks0 + 5u;
#undef TF_RND
  o0 = x0; o1 = x1;
}

__device__ inline float jax_uniform_bn(int f) {
  constexpr int HALF = (B * N) / 2;
  unsigned o0, o1, bits;
  if (f < HALF) { threefry2x32(0u, 42u, (unsigned)f, (unsigned)(f + HALF), o0, o1); bits = o0; }
  else          { threefry2x32(0u, 42u, (unsigned)(f - HALF), (unsigned)f, o0, o1); bits = o1; }
  return __uint_as_float((bits >> 9) | 0x3f800000u) - 1.0f;
}

// ---------------- bf16 split helpers ----------------
__device__ __forceinline__ u16 bf16rn(float f) {
  unsigned u = __float_as_uint(f);
  unsigned r = u + 0x7FFFu + ((u >> 16) & 1u);
  return (u16)(r >> 16);
}
__device__ __forceinline__ float bf16tof(u16 h) {
  return __uint_as_float(((unsigned)h) << 16);
}

// ---------------- prep: sq + hi/lo split + init (one wave per row) ----------------
__global__ __launch_bounds__(64) void k_prep(const float* __restrict__ x, float* __restrict__ sq,
                                             u16* __restrict__ xhi, u16* __restrict__ xlo,
                                             int* __restrict__ counts,
                                             unsigned long long* __restrict__ packed,
                                             float* __restrict__ distmax) {
  int row = blockIdx.x;   // 0..B*N-1
  int lane = threadIdx.x;
  const float* xr = x + (size_t)row * C;
  u16* hr = xhi + (size_t)row * C;
  u16* lr = xlo + (size_t)row * C;
  float s = 0.f;
  for (int c = lane * 4; c < C; c += 256) {
    float4 v = *(const float4*)(xr + c);
    s += v.x * v.x + v.y * v.y + v.z * v.z + v.w * v.w;
    u16 h0 = bf16rn(v.x), h1 = bf16rn(v.y), h2 = bf16rn(v.z), h3 = bf16rn(v.w);
    u16 l0 = bf16rn(v.x - bf16tof(h0));
    u16 l1 = bf16rn(v.y - bf16tof(h1));
    u16 l2 = bf16rn(v.z - bf16tof(h2));
    u16 l3 = bf16rn(v.w - bf16tof(h3));
    uint2 hp, lp;
    hp.x = (unsigned)h0 | ((unsigned)h1 << 16); hp.y = (unsigned)h2 | ((unsigned)h3 << 16);
    lp.x = (unsigned)l0 | ((unsigned)l1 << 16); lp.y = (unsigned)l2 | ((unsigned)l3 << 16);
    *(uint2*)(hr + c) = hp;
    *(uint2*)(lr + c) = lp;
  }
  for (int o = 32; o > 0; o >>= 1) s += __shfl_down(s, o, 64);
  if (lane == 0) {
    sq[row] = s;
    packed[row] = ~0ull;
    if (row < B * CL) counts[row] = 0;
    if (row < B) distmax[row] = 0.f;
  }
}

// ---------------- branchless sorted-insert of v into ascending t[0..4] ----------------
__device__ __forceinline__ void ins5b(float t[5], float v) {
  float c = v;
  float n;
  n = fminf(t[0], c); c = fmaxf(t[0], c); t[0] = n;
  n = fminf(t[1], c); c = fmaxf(t[1], c); t[1] = n;
  n = fminf(t[2], c); c = fmaxf(t[2], c); t[2] = n;
  n = fminf(t[3], c); c = fmaxf(t[3], c); t[3] = n;
  t[4] = fminf(t[4], c);
}

constexpr int NT3 = N / 128;                   // 24
constexpr int NTILE3 = NT3 * (NT3 + 1) / 2;    // 300

// ---------------- dist GEMM (3-term bf16 MFMA), 128x128 tile ----------------
// Round-3: occupancy push. A-operand moved out of LDS (per-lane 16B global
// reads, L1-served 2x intra-block reuse). B-only LDS double buffer
// (2 x 16KB) + epilogue transpose (38.5KB) -> 39424B LDS decl -> 4 blocks/CU
// (was 2). Counted-vmcnt kept: A-loads issued BEFORE the 4 B-DMAs, so the
// phase wait is vmcnt(4) and the compiler's own A-wait is also vmcnt(4)
// (tightest scoreboard count) -> no drain. sched_barrier(0) pins loads
// inside their phase so the count stays exact.
__global__ __launch_bounds__(256, 4) void k_distm(const u16* __restrict__ xhi, const u16* __restrict__ xlo,
                                                  const float* __restrict__ sq,
                                                  float* __restrict__ distbuf,
                                                  float* __restrict__ part5, int b0) {
  // staging layout (u16 units): buf(2) x [ Bh(4096) | Bl(4096) ] = 32KB
  // epilogue reuses the same LDS as 4 x 32 x 77 floats = 39424B
  __shared__ __align__(16) char smem[39424];
  u16* smem_u16 = (u16*)smem;

  int bl = blockIdx.y, b = b0 + bl;

  // bijective XCD swizzle over the 300 tiles of this batch-slice
  int bx = blockIdx.x;
  constexpr int NX = 8, QX = NTILE3 / NX, RX = NTILE3 % NX;  // 37, 4
  int xcd = bx % NX, sub = bx / NX;
  int idx = (xcd < RX ? xcd * (QX + 1) : RX * (QX + 1) + (xcd - RX) * QX) + sub;

  int ti = 0, rem = idx;
  while (rem >= NT3 - ti) { rem -= NT3 - ti; ++ti; }
  int tj = ti + rem;
  int i0 = ti * 128, j0 = tj * 128;
  bool do_mirror = (ti != tj);

  const float* sqb = sq + (size_t)b * N;
  float* dist = distbuf + (size_t)bl * N * N;

  int tid = threadIdx.x;
  int lane = tid & 63, w = tid >> 6;
  int wr = (w >> 1) * 64, wc = (w & 1) * 64;
  int l15 = lane & 15, l4 = lane >> 4;
  int csw = (lane >> 1) & 3;           // read-side chunk swizzle (row bits 1-2)

  // B staging: wave w stages 4 chunks (16 rows x 32 u16 = 1KB each).
  // waves 0,1 -> Bh (rows 0..63 / 64..127), waves 2,3 -> Bl.
  // global source chunk pre-swizzled: chunk ^= (row>>1)&3 == (lane>>3)&3.
  const u16* hilB = (w < 2) ? xhi : xlo;
  const u16* gsrcB = hilB + ((size_t)b * N + j0 + (w & 1) * 64 + (lane >> 2)) * C
                          + ((lane & 3) ^ ((lane >> 3) & 3)) * 8;
  int ldsB = w * 2048;                 // u16 offset of this wave's 4 chunks

  // A fragment row offsets (per-lane element offsets into xhi/xlo)
  size_t aoff[4];
#pragma unroll
  for (int rt = 0; rt < 4; ++rt)
    aoff[rt] = ((size_t)b * N + i0 + wr + rt * 16 + l15) * C + l4 * 8;

  f32x4 acc[4][4];
#pragma unroll
  for (int rt = 0; rt < 4; ++rt)
#pragma unroll
    for (int ct = 0; ct < 4; ++ct)
#pragma unroll
      for (int e = 0; e < 4; ++e) acc[rt][ct][e] = 0.f;

  // prologue: stage B buf0 for step 0 (no wait; first KSTEP waits vmcnt(4))
  {
#pragma unroll
    for (int q = 0; q < 4; ++q)
      __builtin_amdgcn_global_load_lds(
          (const __attribute__((address_space(1))) void*)(gsrcB + q * 16 * C),
          (__attribute__((address_space(3))) void*)(smem_u16 + ldsB + q * 512), 16, 0, 0);
  }

#define KSTEP(CUR, STG, K0A, KNXT, DO_STAGE)                                         \
  {                                                                                  \
    s16x8 ah[4], al[4];                                                              \
    _Pragma("unroll")                                                                \
    for (int rt = 0; rt < 4; ++rt) {                                                 \
      ah[rt] = *(const s16x8*)(xhi + aoff[rt] + (K0A));                              \
      al[rt] = *(const s16x8*)(xlo + aoff[rt] + (K0A));                              \
    }                                                                                \
    if (DO_STAGE) {                                                                  \
      const u16* gs = gsrcB + (KNXT);                                                \
      u16* lb = smem_u16 + (STG) * 8192 + ldsB;                                      \
      _Pragma("unroll")                                                              \
      for (int q = 0; q < 4; ++q)                                                    \
        __builtin_amdgcn_global_load_lds(                                            \
            (const __attribute__((address_space(1))) void*)(gs + q * 16 * C),        \
            (__attribute__((address_space(3))) void*)(lb + q * 512), 16, 0, 0);      \
      asm volatile("s_waitcnt vmcnt(4)" ::: "memory");                               \
    } else {                                                                         \
      asm volatile("s_waitcnt vmcnt(0)" ::: "memory");                               \
    }                                                                                \
    __builtin_amdgcn_s_barrier();                                                    \
    asm volatile("" ::: "memory");                                                   \
    __builtin_amdgcn_sched_barrier(0);                                               \
    const u16* sb = smem_u16 + (CUR) * 8192;                                         \
    _Pragma("unroll")                                                                \
    for (int ct = 0; ct < 4; ++ct) {                                                 \
      int co = (wc + ct * 16 + l15) * 32 + (l4 ^ csw) * 8;                           \
      s16x8 bh = *(const s16x8*)(sb + co);                                           \
      s16x8 bl = *(const s16x8*)(sb + 4096 + co);                                    \
      _Pragma("unroll")                                                              \
      for (int rt = 0; rt < 4; ++rt) {                                               \
        acc[rt][ct] = __builtin_amdgcn_mfma_f32_16x16x32_bf16(ah[rt], bh, acc[rt][ct], 0, 0, 0); \
        acc[rt][ct] = __builtin_amdgcn_mfma_f32_16x16x32_bf16(ah[rt], bl, acc[rt][ct], 0, 0, 0); \
        acc[rt][ct] = __builtin_amdgcn_mfma_f32_16x16x32_bf16(al[rt], bh, acc[rt][ct], 0, 0, 0); \
      }                                                                              \
    }                                                                                \
    __builtin_amdgcn_sched_barrier(0);                                               \
    asm volatile("" ::: "memory");                                                   \
    __builtin_amdgcn_s_barrier();                                                    \
    asm volatile("" ::: "memory");                                                   \
  }

  for (int ks = 0; ks < 16; ks += 2) {
    KSTEP(0, 1, ks * 32, (ks + 1) * 32, true)
    KSTEP(1, 0, (ks + 1) * 32, (ks + 2) * 32, (ks + 2 < 16))
  }
#undef KSTEP

  const float SQC = 22.627416997969522f;
  float sqi[4][4], sqj[4];
#pragma unroll
  for (int rt = 0; rt < 4; ++rt)
#pragma unroll
    for (int r = 0; r < 4; ++r) sqi[rt][r] = sqb[i0 + wr + rt * 16 + l4 * 4 + r];
#pragma unroll
  for (int ct = 0; ct < 4; ++ct) sqj[ct] = sqb[j0 + wc + ct * 16 + l15];

#pragma unroll
  for (int rt = 0; rt < 4; ++rt)
#pragma unroll
    for (int ct = 0; ct < 4; ++ct)
#pragma unroll
      for (int r = 0; r < 4; ++r) {
        float d2 = fmaxf(sqi[rt][r] + sqj[ct] - 2.0f * acc[rt][ct][r], 0.0f);
        acc[rt][ct][r] = sqrtf(d2) / SQC;
      }

  // ---- epilogue: per-wave LDS transpose (32-col passes):
  //  (a) coalesced float4 direct + mirror dist writes
  //  (b) per-row 5-NN partials
  constexpr int TSTR = 77;   // odd dword stride: column scans are conflict-free
  float* sT = (float*)smem + w * (32 * TSTR);

  float t5A[5] = {FLT_MAX, FLT_MAX, FLT_MAX, FLT_MAX, FLT_MAX};
  float mxA = 0.f;

#pragma unroll
  for (int p = 0; p < 2; ++p) {
#pragma unroll
    for (int cth = 0; cth < 2; ++cth) {
      int ct = p * 2 + cth;
      int cl = cth * 16 + l15;
#pragma unroll
      for (int rt = 0; rt < 4; ++rt)
#pragma unroll
        for (int r = 0; r < 4; ++r)
          sT[cl * TSTR + rt * 16 + l4 * 4 + r] = acc[rt][ct][r];
    }
    // direct write
    {
      int g4 = lane & 7, rbase = lane >> 3;
#pragma unroll
      for (int it = 0; it < 8; ++it) {
        int rl = it * 8 + rbase;
        float4 v = make_float4(sT[(4 * g4 + 0) * TSTR + rl],
                               sT[(4 * g4 + 1) * TSTR + rl],
                               sT[(4 * g4 + 2) * TSTR + rl],
                               sT[(4 * g4 + 3) * TSTR + rl]);
        *(float4*)(dist + (size_t)(i0 + wr + rl) * N + j0 + wc + p * 32 + 4 * g4) = v;
      }
    }
    // mirror write (scalar LDS reads: TSTR=77 breaks float4 alignment, and
    // the scalar pattern is <=2-way on banks)
    if (do_mirror) {
      int cg = lane >> 4, rq = lane & 15;
#pragma unroll
      for (int cc = 0; cc < 8; ++cc) {
        int c = cc * 4 + cg;
        float4 v;
        v.x = sT[c * TSTR + rq * 4 + 0];
        v.y = sT[c * TSTR + rq * 4 + 1];
        v.z = sT[c * TSTR + rq * 4 + 2];
        v.w = sT[c * TSTR + rq * 4 + 3];
        *(float4*)(dist + (size_t)(j0 + wc + p * 32 + c) * N + i0 + wr + rq * 4) = v;
      }
    }
    // (b1) A-side partial scan
    for (int c = 0; c < 32; ++c) {
      float v = sT[c * TSTR + lane];
      mxA = fmaxf(mxA, v);
      ins5b(t5A, v);
    }
    // (b2) mirror-side partials
    if (do_mirror) {
      int cl = lane & 31, half = lane >> 5;
      float t5B[5] = {FLT_MAX, FLT_MAX, FLT_MAX, FLT_MAX, FLT_MAX};
      float mxB = 0.f;
      for (int k = 0; k < 32; ++k) {
        float v = sT[cl * TSTR + half * 32 + k];
        mxB = fmaxf(mxB, v);
        ins5b(t5B, v);
      }
      mxB = fmaxf(mxB, __shfl_xor(mxB, 32, 64));
      float o0 = __shfl_xor(t5B[0], 32, 64);
      float o1 = __shfl_xor(t5B[1], 32, 64);
      float o2 = __shfl_xor(t5B[2], 32, 64);
      float o3 = __shfl_xor(t5B[3], 32, 64);
      float o4 = __shfl_xor(t5B[4], 32, 64);
      ins5b(t5B, o0); ins5b(t5B, o1); ins5b(t5B, o2); ins5b(t5B, o3); ins5b(t5B, o4);
      if (half == 0) {
        int rowB = j0 + wc + p * 32 + cl;
        int slotB = ti * 2 + (wr >> 6);
        float* dst = part5 + (((size_t)bl * 48 + slotB) * 6) * N + rowB;
        dst[0] = t5B[0]; dst[(size_t)N] = t5B[1]; dst[2 * (size_t)N] = t5B[2];
        dst[3 * (size_t)N] = t5B[3]; dst[4 * (size_t)N] = t5B[4]; dst[5 * (size_t)N] = mxB;
      }
    }
  }
  {
    int rowA = i0 + wr + lane;
    int slotA = tj * 2 + (wc >> 6);
    float* dst = part5 + (((size_t)bl * 48 + slotA) * 6) * N + rowA;
    dst[0] = t5A[0]; dst[(size_t)N] = t5A[1]; dst[2 * (size_t)N] = t5A[2];
    dst[3 * (size_t)N] = t5A[3]; dst[4 * (size_t)N] = t5A[4]; dst[5 * (size_t)N] = mxA;
  }
}

// ---------------- density from 48-slot partials (+ fused distmax atomicMax) ----------------
__global__ __launch_bounds__(256) void k_dens(const float* __restrict__ part5,
                                              float* __restrict__ density,
                                              float* __restrict__ distmax, int b0) {
  int g = blockIdx.x * 256 + threadIdx.x;   // bl*N + r
  int bl = g / N, r = g % N;
  int b = b0 + bl;
  const float* base = part5 + (size_t)bl * 48 * 6 * N + r;
  float t5[5] = {FLT_MAX, FLT_MAX, FLT_MAX, FLT_MAX, FLT_MAX};
  float mx = 0.f;
  for (int s = 0; s < 48; ++s) {
    const float* sp = base + (size_t)s * 6 * N;
    ins5b(t5, sp[0]);
    ins5b(t5, sp[(size_t)N]);
    ins5b(t5, sp[2 * (size_t)N]);
    ins5b(t5, sp[3 * (size_t)N]);
    ins5b(t5, sp[4 * (size_t)N]);
    mx = fmaxf(mx, sp[5 * (size_t)N]);
  }
  float sum = t5[0] * t5[0] + t5[1] * t5[1] + t5[2] * t5[2] + t5[3] * t5[3] + t5[4] * t5[4];
  density[b * N + r] = expf(-(sum / 5.0f)) + jax_uniform_bn(b * N + r) * 1e-6f;
  // fused distmax: wave-reduce then one int-atomicMax per wave (dist >= 0 so
  // positive-float bit order == int order). Init done in k_prep.
#pragma unroll
  for (int m = 1; m < 64; m <<= 1) mx = fmaxf(mx, __shfl_xor(mx, m, 64));
  if ((threadIdx.x & 63) == 0) atomicMax((int*)(distmax + b), __float_as_int(mx));
}

// ---------------- masked min -> score (4 rows per wave, 16 per block) ----------------
__global__ __launch_bounds__(256) void k_maskmin(const float* __restrict__ distbuf,
                                                 const float* __restrict__ density,
                                                 const float* __restrict__ distmax,
                                                 float* __restrict__ score, int b0) {
  __shared__ float sd[N];
  int tid = threadIdx.x;
  int wv = tid >> 6, lane = tid & 63;
  int bl = blockIdx.y, b = b0 + bl;
  const float* db = density + (size_t)b * N;
  for (int j = tid * 4; j < N; j += 1024) *(float4*)(sd + j) = *(const float4*)(db + j);
  __syncthreads();
  int i0r = blockIdx.x * 16 + wv * 4;
  float dmax = distmax[b];
  const float* row0 = distbuf + ((size_t)bl * N + i0r) * N;
  float di0 = sd[i0r], di1 = sd[i0r + 1], di2 = sd[i0r + 2], di3 = sd[i0r + 3];
  float mn0 = dmax, mn1 = dmax, mn2 = dmax, mn3 = dmax;
#pragma unroll 2
  for (int it = 0; it < N / 256; ++it) {
    int j = it * 256 + lane * 4;
    float4 d  = *(const float4*)(sd + j);
    float4 v0 = *(const float4*)(row0 + j);
    float4 v1 = *(const float4*)(row0 + (size_t)N + j);
    float4 v2 = *(const float4*)(row0 + 2 * (size_t)N + j);
    float4 v3 = *(const float4*)(row0 + 3 * (size_t)N + j);
    mn0 = fminf(mn0, (d.x > di0) ? v0.x : dmax);
    mn0 = fminf(mn0, (d.y > di0) ? v0.y : dmax);
    mn0 = fminf(mn0, (d.z > di0) ? v0.z : dmax);
    mn0 = fminf(mn0, (d.w > di0) ? v0.w : dmax);
    mn1 = fminf(mn1, (d.x > di1) ? v1.x : dmax);
    mn1 = fminf(mn1, (d.y > di1) ? v1.y : dmax);
    mn1 = fminf(mn1, (d.z > di1) ? v1.z : dmax);
    mn1 = fminf(mn1, (d.w > di1) ? v1.w : dmax);
    mn2 = fminf(mn2, (d.x > di2) ? v2.x : dmax);
    mn2 = fminf(mn2, (d.y > di2) ? v2.y : dmax);
    mn2 = fminf(mn2, (d.z > di2) ? v2.z : dmax);
    mn2 = fminf(mn2, (d.w > di2) ? v2.w : dmax);
    mn3 = fminf(mn3, (d.x > di3) ? v3.x : dmax);
    mn3 = fminf(mn3, (d.y > di3) ? v3.y : dmax);
    mn3 = fminf(mn3, (d.z > di3) ? v3.z : dmax);
    mn3 = fminf(mn3, (d.w > di3) ? v3.w : dmax);
  }
#pragma unroll
  for (int m = 1; m < 64; m <<= 1) {
    mn0 = fminf(mn0, __shfl_xor(mn0, m, 64));
    mn1 = fminf(mn1, __shfl_xor(mn1, m, 64));
    mn2 = fminf(mn2, __shfl_xor(mn2, m, 64));
    mn3 = fminf(mn3, __shfl_xor(mn3, m, 64));
  }
  if (lane == 0) {
    score[b * N + i0r]     = mn0 * di0;
    score[b * N + i0r + 1] = mn1 * di1;
    score[b * N + i0r + 2] = mn2 * di2;
    score[b * N + i0r + 3] = mn3 * di3;
  }
}

// ---------------- counting-rank top-CL (4 rows per wave, 16 per block) ----------------
__global__ __launch_bounds__(256) void k_rank(const float* __restrict__ score,
                                              int* __restrict__ index_down,
                                              int* __restrict__ rank, int b0) {
  __shared__ float ssc[N];
  int tid = threadIdx.x;
  int wv = tid >> 6, lane = tid & 63;
  int b = b0 + blockIdx.y;
  const float* sb = score + (size_t)b * N;
  for (int j = tid * 4; j < N; j += 1024) *(float4*)(ssc + j) = *(const float4*)(sb + j);
  __syncthreads();
  int i0r = blockIdx.x * 16 + wv * 4;
  float s0 = ssc[i0r], s1 = ssc[i0r + 1], s2 = ssc[i0r + 2], s3 = ssc[i0r + 3];
  int c0 = 0, c1 = 0, c2 = 0, c3 = 0;
#pragma unroll 2
  for (int it = 0; it < N / 256; ++it) {
    int j = it * 256 + lane * 4;
    float4 v = *(const float4*)(ssc + j);
    c0 += (v.x > s0) || (v.x == s0 && (j + 0) < i0r);
    c0 += (v.y > s0) || (v.y == s0 && (j + 1) < i0r);
    c0 += (v.z > s0) || (v.z == s0 && (j + 2) < i0r);
    c0 += (v.w > s0) || (v.w == s0 && (j + 3) < i0r);
    c1 += (v.x > s1) || (v.x == s1 && (j + 0) < i0r + 1);
    c1 += (v.y > s1) || (v.y == s1 && (j + 1) < i0r + 1);
    c1 += (v.z > s1) || (v.z == s1 && (j + 2) < i0r + 1);
    c1 += (v.w > s1) || (v.w == s1 && (j + 3) < i0r + 1);
    c2 += (v.x > s2) || (v.x == s2 && (j + 0) < i0r + 2);
    c2 += (v.y > s2) || (v.y == s2 && (j + 1) < i0r + 2);
    c2 += (v.z > s2) || (v.z == s2 && (j + 2) < i0r + 2);
    c2 += (v.w > s2) || (v.w == s2 && (j + 3) < i0r + 2);
    c3 += (v.x > s3) || (v.x == s3 && (j + 0) < i0r + 3);
    c3 += (v.y > s3) || (v.y == s3 && (j + 1) < i0r + 3);
    c3 += (v.z > s3) || (v.z == s3 && (j + 2) < i0r + 3);
    c3 += (v.w > s3) || (v.w == s3 && (j + 3) < i0r + 3);
  }
#pragma unroll
  for (int m = 1; m < 64; m <<= 1) {
    c0 += __shfl_xor(c0, m, 64);
    c1 += __shfl_xor(c1, m, 64);
    c2 += __shfl_xor(c2, m, 64);
    c3 += __shfl_xor(c3, m, 64);
  }
  if (lane == 0) {
    rank[b * N + i0r]     = (c0 < CL) ? c0 : -1;
    rank[b * N + i0r + 1] = (c1 < CL) ? c1 : -1;
    rank[b * N + i0r + 2] = (c2 < CL) ? c2 : -1;
    rank[b * N + i0r + 3] = (c3 < CL) ? c3 : -1;
    if (c0 < CL) index_down[b * CL + c0] = i0r;
    if (c1 < CL) index_down[b * CL + c1] = i0r + 1;
    if (c2 < CL) index_down[b * CL + c2] = i0r + 2;
    if (c3 < CL) index_down[b * CL + c3] = i0r + 3;
  }
}

// ---------------- assignment: chunked center rows + packed atomicMin ----------------
__global__ __launch_bounds__(256) void k_assign_part(const float* __restrict__ distbuf,
                                                     const int* __restrict__ index_down,
                                                     unsigned long long* __restrict__ packed, int b0) {
  constexpr int RCH = CL / 8;  // 96
  __shared__ int sid[RCH];
  int bl = blockIdx.z, b = b0 + bl;
  int r0 = blockIdx.y * RCH;
  int tid = threadIdx.x;
  for (int r = tid; r < RCH; r += 256) sid[r] = index_down[b * CL + r0 + r];
  __syncthreads();
  int j = blockIdx.x * 256 + tid;
  const float* base = distbuf + (size_t)bl * N * N;
  float best = FLT_MAX; int bestr = 0;
#pragma unroll 8
  for (int r = 0; r < RCH; ++r) {
    float d = base[(size_t)sid[r] * N + j];
    if (d < best) { best = d; bestr = r0 + r; }
  }
  unsigned long long key = ((unsigned long long)__float_as_uint(best) << 32) | (unsigned)bestr;
  atomicMin(&packed[b * N + j], key);
}

__global__ void k_assign_fin2(const unsigned long long* __restrict__ packed,
                              const int* __restrict__ rank,
                              int* __restrict__ idx_cluster, int* __restrict__ counts) {
  int g = blockIdx.x * 256 + threadIdx.x;
  int b = g / N;
  int r = rank[g];
  int cl = (r >= 0) ? r : (int)(unsigned)(packed[g] & 0xffffffffull);
  idx_cluster[g] = cl;
  atomicAdd(&counts[b * CL + cl], 1);
}

// ---------------- merge ----------------
__global__ __launch_bounds__(1024) void k_scan(const int* __restrict__ counts,
                                               int* __restrict__ offsets, int* __restrict__ cursor) {
  constexpr int T = B * CL;
  __shared__ int sm[T];
  int tid = threadIdx.x;
  for (int p = tid; p < T; p += 1024) sm[p] = counts[p];
  __syncthreads();
  for (int off = 1; off < T; off <<= 1) {
    int v[3]; int n = 0;
    for (int p = tid; p < T; p += 1024) { v[n++] = (p >= off) ? sm[p - off] : 0; }
    __syncthreads();
    n = 0;
    for (int p = tid; p < T; p += 1024) { sm[p] += v[n++]; }
    __syncthreads();
  }
  for (int p = tid; p < T; p += 1024) {
    int e = sm[p] - counts[p];
    offsets[p] = e; cursor[p] = e;
  }
}

__global__ void k_fill(const int* __restrict__ idx_cluster, int* __restrict__ cursor,
                       int* __restrict__ members) {
  int g = blockIdx.x * 256 + threadIdx.x;
  int b = g / N, i = g % N;
  int seg = b * CL + idx_cluster[g];
  int pos = atomicAdd(&cursor[seg], 1);
  members[pos] = i;
}

__global__ __launch_bounds__(128) void k_gather(const float* __restrict__ x, const int* __restrict__ members,
                                                const int* __restrict__ offsets, const int* __restrict__ counts,
                                                float* __restrict__ out0) {
  int seg = blockIdx.x;
  int b = seg / CL;
  int cnt = counts[seg], off = offsets[seg];
  float nw = 1.0f / ((float)cnt + 1e-6f);
  int c = threadIdx.x * 4;
  const float* xb = x + (size_t)b * N * C;
  float4 acc = make_float4(0.f, 0.f, 0.f, 0.f);
  for (int m = 0; m < cnt; ++m) {
    int tok = members[off + m];
    float4 v = *(const float4*)(xb + (size_t)tok * C + c);
    acc.x += v.x * nw; acc.y += v.y * nw; acc.z += v.z * nw; acc.w += v.w * nw;
  }
  *(float4*)(out0 + (size_t)seg * C + c) = acc;
}

__global__ void k_final(const float* __restrict__ agg_weight, const int* __restrict__ idx_token,
                        const int* __restrict__ idx_cluster, const int* __restrict__ counts,
                        float* __restrict__ out1, float* __restrict__ out2, float* __restrict__ out3) {
  int g = blockIdx.x * 256 + threadIdx.x;
  int b = g / N;
  int it = idx_token[g];
  int clt = idx_cluster[b * N + it];
  float nwt = 1.0f / ((float)counts[b * CL + clt] + 1e-6f);
  out1[g] = agg_weight[g] * nwt;
  out2[g] = (float)clt;
  out3[g] = (float)idx_cluster[g];
}

// ---------------- launch ----------------
extern "C" void kernel_launch(void* const* d_in, const int* in_sizes, int n_in,
                              void* d_out, int out_size, void* d_ws, size_t ws_size,
                              hipStream_t stream) {
  const float* x          = (const float*)d_in[0];
  const int*   idx_token  = (const int*)d_in[1];
  const float* agg_weight = (const float*)d_in[2];

  float* out0 = (float*)d_out;
  float* out1 = out0 + (size_t)B * CL * C;
  float* out2 = out1 + (size_t)B * N;
  float* out3 = out2 + (size_t)B * N;

  char* w = (char*)d_ws;
  auto carve = [&](size_t bytes) { char* p = w; w += (bytes + 255) & ~(size_t)255; return p; };
  float*    sq         = (float*)carve((size_t)B * N * 4);
  float*    density    = (float*)carve((size_t)B * N * 4);
  float*    score      = (float*)carve((size_t)B * N * 4);
  float*    distmax    = (float*)carve((size_t)B * 4);
  int*      index_down = (int*)carve((size_t)B * CL * 4);
  int*      rank       = (int*)carve((size_t)B * N * 4);
  int*      idx_clus   = (int*)carve((size_t)B * N * 4);
  int*      counts     = (int*)carve((size_t)B * CL * 4);
  int*      offsets    = (int*)carve((size_t)B * CL * 4);
  int*      cursor     = (int*)carve((size_t)B * CL * 4);
  int*      members    = (int*)carve((size_t)B * N * 4);
  unsigned long long* packed = (unsigned long long*)carve((size_t)B * N * 8);
  u16*      xhi        = (u16*)carve((size_t)B * N * C * 2);
  u16*      xlo        = (u16*)carve((size_t)B * N * C * 2);
  float*    part5      = (float*)carve((size_t)B * 48 * 6 * N * 4);
  size_t used = (size_t)(w - (char*)d_ws);
  size_t per  = (size_t)N * N * 4;
  int nb_max = (ws_size > used) ? (int)((ws_size - used) / per) : 0;
  if (nb_max < 1) nb_max = 1;
  if (nb_max > B) nb_max = B;
  float* distbuf = (float*)w;

  k_prep<<<B * N, 64, 0, stream>>>(x, sq, xhi, xlo, counts, packed, distmax);

  for (int b0 = 0; b0 < B; b0 += nb_max) {
    int nb = (B - b0 < nb_max) ? (B - b0) : nb_max;
    k_distm<<<dim3(NTILE3, nb), 256, 0, stream>>>(xhi, xlo, sq, distbuf, part5, b0);
    k_dens<<<(nb * N) / 256, 256, 0, stream>>>(part5, density, distmax, b0);
    k_maskmin<<<dim3(N / 16, nb), 256, 0, stream>>>(distbuf, density, distmax, score, b0);
    k_rank<<<dim3(N / 16, nb), 256, 0, stream>>>(score, index_down, rank, b0);
    k_assign_part<<<dim3(N / 256, 8, nb), 256, 0, stream>>>(distbuf, index_down, packed, b0);
  }

  k_assign_fin2<<<(B * N) / 256, 256, 0, stream>>>(packed, rank, idx_clus, counts);
  k_scan<<<1, 1024, 0, stream>>>(counts, offsets, cursor);
  k_fill<<<(B * N) / 256, 256, 0, stream>>>(idx_clus, cursor, members);
  k_gather<<<B * CL, 128, 0, stream>>>(x, members, offsets, counts, out0);
  k_final<<<(B * N) / 256, 256, 0, stream>>>(agg_weight, idx_token, idx_clus, counts, out1, out2, out3);
}

// Round 6
// 335.965 us; speedup vs baseline: 1.1767x; 1.1767x over previous
//
#include <hip/hip_runtime.h>
#include <math.h>
#include <float.h>

constexpr int B  = 4;
constexpr int N  = 3072;
constexpr int C  = 512;
constexpr int CL = 768;

typedef unsigned short u16;
typedef __attribute__((ext_vector_type(8))) short s16x8;
typedef __attribute__((ext_vector_type(4))) float f32x4;

// ---------------- JAX threefry2x32 (exact) ----------------
__device__ __forceinline__ unsigned rotl32(unsigned v, int d) { return (v << d) | (v >> (32 - d)); }

__device__ inline void threefry2x32(unsigned k0, unsigned k1, unsigned c0, unsigned c1,
                                    unsigned& o0, unsigned& o1) {
  unsigned ks0 = k0, ks1 = k1, ks2 = 0x1BD11BDAu ^ k0 ^ k1;
  unsigned x0 = c0 + ks0, x1 = c1 + ks1;
#define TF_RND(r) { x0 += x1; x1 = rotl32(x1, (r)); x1 ^= x0; }
  TF_RND(13) TF_RND(15) TF_RND(26) TF_RND(6)  x0 += ks1; x1 += ks2 + 1u;
  TF_RND(17) TF_RND(29) TF_RND(16) TF_RND(24) x0 += ks2; x1 += ks0 + 2u;
  TF_RND(13) TF_RND(15) TF_RND(26) TF_RND(6)  x0 += ks0; x1 += ks1 + 3u;
  TF_RND(17) TF_RND(29) TF_RND(16) TF_RND(24) x0 += ks1; x1 += ks2 + 4u;
  TF_RND(13) TF_RND(15) TF_RND(26) TF_RND(6)  x0 += ks2; x1 += ks0 + 5u;
#undef TF_RND
  o0 = x0; o1 = x1;
}

__device__ inline float jax_uniform_bn(int f) {
  constexpr int HALF = (B * N) / 2;
  unsigned o0, o1, bits;
  if (f < HALF) { threefry2x32(0u, 42u, (unsigned)f, (unsigned)(f + HALF), o0, o1); bits = o0; }
  else          { threefry2x32(0u, 42u, (unsigned)(f - HALF), (unsigned)f, o0, o1); bits = o1; }
  return __uint_as_float((bits >> 9) | 0x3f800000u) - 1.0f;
}

// ---------------- bf16 split helpers ----------------
__device__ __forceinline__ u16 bf16rn(float f) {
  unsigned u = __float_as_uint(f);
  unsigned r = u + 0x7FFFu + ((u >> 16) & 1u);
  return (u16)(r >> 16);
}
__device__ __forceinline__ float bf16tof(u16 h) {
  return __uint_as_float(((unsigned)h) << 16);
}

// ---------------- prep: sq + hi/lo split + init (one wave per row) ----------------
__global__ __launch_bounds__(64) void k_prep(const float* __restrict__ x, float* __restrict__ sq,
                                             u16* __restrict__ xhi, u16* __restrict__ xlo,
                                             int* __restrict__ counts,
                                             unsigned long long* __restrict__ packed,
                                             float* __restrict__ distmax) {
  int row = blockIdx.x;   // 0..B*N-1
  int lane = threadIdx.x;
  const float* xr = x + (size_t)row * C;
  u16* hr = xhi + (size_t)row * C;
  u16* lr = xlo + (size_t)row * C;
  float s = 0.f;
  for (int c = lane * 4; c < C; c += 256) {
    float4 v = *(const float4*)(xr + c);
    s += v.x * v.x + v.y * v.y + v.z * v.z + v.w * v.w;
    u16 h0 = bf16rn(v.x), h1 = bf16rn(v.y), h2 = bf16rn(v.z), h3 = bf16rn(v.w);
    u16 l0 = bf16rn(v.x - bf16tof(h0));
    u16 l1 = bf16rn(v.y - bf16tof(h1));
    u16 l2 = bf16rn(v.z - bf16tof(h2));
    u16 l3 = bf16rn(v.w - bf16tof(h3));
    uint2 hp, lp;
    hp.x = (unsigned)h0 | ((unsigned)h1 << 16); hp.y = (unsigned)h2 | ((unsigned)h3 << 16);
    lp.x = (unsigned)l0 | ((unsigned)l1 << 16); lp.y = (unsigned)l2 | ((unsigned)l3 << 16);
    *(uint2*)(hr + c) = hp;
    *(uint2*)(lr + c) = lp;
  }
  for (int o = 32; o > 0; o >>= 1) s += __shfl_down(s, o, 64);
  if (lane == 0) {
    sq[row] = s;
    packed[row] = ~0ull;
    if (row < B * CL) counts[row] = 0;
    if (row < B) distmax[row] = 0.f;
  }
}

// ---------------- branchless sorted-insert of v into ascending t[0..4] ----------------
__device__ __forceinline__ void ins5b(float t[5], float v) {
  float c = v;
  float n;
  n = fminf(t[0], c); c = fmaxf(t[0], c); t[0] = n;
  n = fminf(t[1], c); c = fmaxf(t[1], c); t[1] = n;
  n = fminf(t[2], c); c = fmaxf(t[2], c); t[2] = n;
  n = fminf(t[3], c); c = fmaxf(t[3], c); t[3] = n;
  t[4] = fminf(t[4], c);
}

constexpr int NT3 = N / 128;                   // 24
constexpr int NTILE3 = NT3 * (NT3 + 1) / 2;    // 300

// ---------------- dist GEMM (3-term bf16 MFMA), 128x128 tile ----------------
// Round-5 resubmit (round-5 bench was an infra failure, no data):
//  (a) __launch_bounds__(256,3): r4's (256,4) capped regs at 128/wave ->
//      scratch spill (WRITE 161->265MB). 3 waves/SIMD gives ~168 budget:
//      64 acc + 64 A-frags + addressing fits. 3 blocks/CU (LDS 118KB).
//  (b) A-frags double-buffered one K-step ahead (ping-pong reg sets):
//      phase k issues A(k+1)+DMA(k+1) [12 ops], waits vmcnt(12) ->
//      A(k),DMA(k) complete, this phase's 12 stay in flight.
__global__ __launch_bounds__(256, 3) void k_distm(const u16* __restrict__ xhi, const u16* __restrict__ xlo,
                                                  const float* __restrict__ sq,
                                                  float* __restrict__ distbuf,
                                                  float* __restrict__ part5, int b0) {
  // staging layout (u16 units): buf(2) x [ Bh(4096) | Bl(4096) ] = 32KB
  // epilogue reuses the same LDS as 4 x 32 x 77 floats = 39424B
  __shared__ __align__(16) char smem[39424];
  u16* smem_u16 = (u16*)smem;

  int bl = blockIdx.y, b = b0 + bl;

  // bijective XCD swizzle over the 300 tiles of this batch-slice
  int bx = blockIdx.x;
  constexpr int NX = 8, QX = NTILE3 / NX, RX = NTILE3 % NX;  // 37, 4
  int xcd = bx % NX, sub = bx / NX;
  int idx = (xcd < RX ? xcd * (QX + 1) : RX * (QX + 1) + (xcd - RX) * QX) + sub;

  int ti = 0, rem = idx;
  while (rem >= NT3 - ti) { rem -= NT3 - ti; ++ti; }
  int tj = ti + rem;
  int i0 = ti * 128, j0 = tj * 128;
  bool do_mirror = (ti != tj);

  const float* sqb = sq + (size_t)b * N;
  float* dist = distbuf + (size_t)bl * N * N;

  int tid = threadIdx.x;
  int lane = tid & 63, w = tid >> 6;
  int wr = (w >> 1) * 64, wc = (w & 1) * 64;
  int l15 = lane & 15, l4 = lane >> 4;
  int csw = (lane >> 1) & 3;           // read-side chunk swizzle (row bits 1-2)

  // B staging: wave w stages 4 chunks (16 rows x 32 u16 = 1KB each).
  // waves 0,1 -> Bh (rows 0..63 / 64..127), waves 2,3 -> Bl.
  // global source chunk pre-swizzled: chunk ^= (row>>1)&3 == (lane>>3)&3.
  const u16* hilB = (w < 2) ? xhi : xlo;
  const u16* gsrcB = hilB + ((size_t)b * N + j0 + (w & 1) * 64 + (lane >> 2)) * C
                          + ((lane & 3) ^ ((lane >> 3) & 3)) * 8;
  int ldsB = w * 2048;                 // u16 offset of this wave's 4 chunks

  // A fragment row offsets (per-lane element offsets into xhi/xlo)
  size_t aoff[4];
#pragma unroll
  for (int rt = 0; rt < 4; ++rt)
    aoff[rt] = ((size_t)b * N + i0 + wr + rt * 16 + l15) * C + l4 * 8;

  f32x4 acc[4][4];
#pragma unroll
  for (int rt = 0; rt < 4; ++rt)
#pragma unroll
    for (int ct = 0; ct < 4; ++ct)
#pragma unroll
      for (int e = 0; e < 4; ++e) acc[rt][ct][e] = 0.f;

  s16x8 ahA[4], alA[4], ahB[4], alB[4];

  // prologue: A(0) -> set A; stage B buf0 (no wait; first phase waits vmcnt(12))
#pragma unroll
  for (int rt = 0; rt < 4; ++rt) {
    ahA[rt] = *(const s16x8*)(xhi + aoff[rt]);
    alA[rt] = *(const s16x8*)(xlo + aoff[rt]);
  }
#pragma unroll
  for (int q = 0; q < 4; ++q)
    __builtin_amdgcn_global_load_lds(
        (const __attribute__((address_space(1))) void*)(gsrcB + q * 16 * C),
        (__attribute__((address_space(3))) void*)(smem_u16 + ldsB + q * 512), 16, 0, 0);

#define KSTEP(CUR, STG, LD, US, KNXT, DO_PRE)                                        \
  {                                                                                  \
    if (DO_PRE) {                                                                    \
      _Pragma("unroll")                                                              \
      for (int rt = 0; rt < 4; ++rt) {                                               \
        ah##LD[rt] = *(const s16x8*)(xhi + aoff[rt] + (KNXT));                       \
        al##LD[rt] = *(const s16x8*)(xlo + aoff[rt] + (KNXT));                       \
      }                                                                              \
      const u16* gs = gsrcB + (KNXT);                                                \
      u16* lb = smem_u16 + (STG) * 8192 + ldsB;                                      \
      _Pragma("unroll")                                                              \
      for (int q = 0; q < 4; ++q)                                                    \
        __builtin_amdgcn_global_load_lds(                                            \
            (const __attribute__((address_space(1))) void*)(gs + q * 16 * C),        \
            (__attribute__((address_space(3))) void*)(lb + q * 512), 16, 0, 0);      \
      asm volatile("s_waitcnt vmcnt(12)" ::: "memory");                              \
    } else {                                                                         \
      asm volatile("s_waitcnt vmcnt(0)" ::: "memory");                               \
    }                                                                                \
    __builtin_amdgcn_s_barrier();                                                    \
    asm volatile("" ::: "memory");                                                   \
    __builtin_amdgcn_sched_barrier(0);                                               \
    const u16* sb = smem_u16 + (CUR) * 8192;                                         \
    _Pragma("unroll")                                                                \
    for (int ct = 0; ct < 4; ++ct) {                                                 \
      int co = (wc + ct * 16 + l15) * 32 + (l4 ^ csw) * 8;                           \
      s16x8 bh = *(const s16x8*)(sb + co);                                           \
      s16x8 bl = *(const s16x8*)(sb + 4096 + co);                                    \
      _Pragma("unroll")                                                              \
      for (int rt = 0; rt < 4; ++rt) {                                               \
        acc[rt][ct] = __builtin_amdgcn_mfma_f32_16x16x32_bf16(ah##US[rt], bh, acc[rt][ct], 0, 0, 0); \
        acc[rt][ct] = __builtin_amdgcn_mfma_f32_16x16x32_bf16(ah##US[rt], bl, acc[rt][ct], 0, 0, 0); \
        acc[rt][ct] = __builtin_amdgcn_mfma_f32_16x16x32_bf16(al##US[rt], bh, acc[rt][ct], 0, 0, 0); \
      }                                                                              \
    }                                                                                \
    __builtin_amdgcn_sched_barrier(0);                                               \
    asm volatile("" ::: "memory");                                                   \
    __builtin_amdgcn_s_barrier();                                                    \
    asm volatile("" ::: "memory");                                                   \
  }

  for (int ks = 0; ks < 16; ks += 2) {
    KSTEP(0, 1, B, A, (ks + 1) * 32, true)
    KSTEP(1, 0, A, B, (ks + 2) * 32, (ks + 2 < 16))
  }
#undef KSTEP

  const float SQC = 22.627416997969522f;
  float sqi[4][4], sqj[4];
#pragma unroll
  for (int rt = 0; rt < 4; ++rt)
#pragma unroll
    for (int r = 0; r < 4; ++r) sqi[rt][r] = sqb[i0 + wr + rt * 16 + l4 * 4 + r];
#pragma unroll
  for (int ct = 0; ct < 4; ++ct) sqj[ct] = sqb[j0 + wc + ct * 16 + l15];

#pragma unroll
  for (int rt = 0; rt < 4; ++rt)
#pragma unroll
    for (int ct = 0; ct < 4; ++ct)
#pragma unroll
      for (int r = 0; r < 4; ++r) {
        float d2 = fmaxf(sqi[rt][r] + sqj[ct] - 2.0f * acc[rt][ct][r], 0.0f);
        acc[rt][ct][r] = sqrtf(d2) / SQC;
      }

  // ---- epilogue: per-wave LDS transpose (32-col passes):
  //  (a) coalesced float4 direct + mirror dist writes
  //  (b) per-row 5-NN partials
  constexpr int TSTR = 77;   // odd dword stride: column scans are conflict-free
  float* sT = (float*)smem + w * (32 * TSTR);

  float t5A[5] = {FLT_MAX, FLT_MAX, FLT_MAX, FLT_MAX, FLT_MAX};
  float mxA = 0.f;

#pragma unroll
  for (int p = 0; p < 2; ++p) {
#pragma unroll
    for (int cth = 0; cth < 2; ++cth) {
      int ct = p * 2 + cth;
      int cl = cth * 16 + l15;
#pragma unroll
      for (int rt = 0; rt < 4; ++rt)
#pragma unroll
        for (int r = 0; r < 4; ++r)
          sT[cl * TSTR + rt * 16 + l4 * 4 + r] = acc[rt][ct][r];
    }
    // direct write
    {
      int g4 = lane & 7, rbase = lane >> 3;
#pragma unroll
      for (int it = 0; it < 8; ++it) {
        int rl = it * 8 + rbase;
        float4 v = make_float4(sT[(4 * g4 + 0) * TSTR + rl],
                               sT[(4 * g4 + 1) * TSTR + rl],
                               sT[(4 * g4 + 2) * TSTR + rl],
                               sT[(4 * g4 + 3) * TSTR + rl]);
        *(float4*)(dist + (size_t)(i0 + wr + rl) * N + j0 + wc + p * 32 + 4 * g4) = v;
      }
    }
    // mirror write (scalar LDS reads: TSTR=77 breaks float4 alignment, and
    // the scalar pattern is <=2-way on banks)
    if (do_mirror) {
      int cg = lane >> 4, rq = lane & 15;
#pragma unroll
      for (int cc = 0; cc < 8; ++cc) {
        int c = cc * 4 + cg;
        float4 v;
        v.x = sT[c * TSTR + rq * 4 + 0];
        v.y = sT[c * TSTR + rq * 4 + 1];
        v.z = sT[c * TSTR + rq * 4 + 2];
        v.w = sT[c * TSTR + rq * 4 + 3];
        *(float4*)(dist + (size_t)(j0 + wc + p * 32 + c) * N + i0 + wr + rq * 4) = v;
      }
    }
    // (b1) A-side partial scan
    for (int c = 0; c < 32; ++c) {
      float v = sT[c * TSTR + lane];
      mxA = fmaxf(mxA, v);
      ins5b(t5A, v);
    }
    // (b2) mirror-side partials
    if (do_mirror) {
      int cl = lane & 31, half = lane >> 5;
      float t5B[5] = {FLT_MAX, FLT_MAX, FLT_MAX, FLT_MAX, FLT_MAX};
      float mxB = 0.f;
      for (int k = 0; k < 32; ++k) {
        float v = sT[cl * TSTR + half * 32 + k];
        mxB = fmaxf(mxB, v);
        ins5b(t5B, v);
      }
      mxB = fmaxf(mxB, __shfl_xor(mxB, 32, 64));
      float o0 = __shfl_xor(t5B[0], 32, 64);
      float o1 = __shfl_xor(t5B[1], 32, 64);
      float o2 = __shfl_xor(t5B[2], 32, 64);
      float o3 = __shfl_xor(t5B[3], 32, 64);
      float o4 = __shfl_xor(t5B[4], 32, 64);
      ins5b(t5B, o0); ins5b(t5B, o1); ins5b(t5B, o2); ins5b(t5B, o3); ins5b(t5B, o4);
      if (half == 0) {
        int rowB = j0 + wc + p * 32 + cl;
        int slotB = ti * 2 + (wr >> 6);
        float* dst = part5 + (((size_t)bl * 48 + slotB) * 6) * N + rowB;
        dst[0] = t5B[0]; dst[(size_t)N] = t5B[1]; dst[2 * (size_t)N] = t5B[2];
        dst[3 * (size_t)N] = t5B[3]; dst[4 * (size_t)N] = t5B[4]; dst[5 * (size_t)N] = mxB;
      }
    }
  }
  {
    int rowA = i0 + wr + lane;
    int slotA = tj * 2 + (wc >> 6);
    float* dst = part5 + (((size_t)bl * 48 + slotA) * 6) * N + rowA;
    dst[0] = t5A[0]; dst[(size_t)N] = t5A[1]; dst[2 * (size_t)N] = t5A[2];
    dst[3 * (size_t)N] = t5A[3]; dst[4 * (size_t)N] = t5A[4]; dst[5 * (size_t)N] = mxA;
  }
}

// ---------------- density from 48-slot partials (+ fused distmax atomicMax) ----------------
__global__ __launch_bounds__(256) void k_dens(const float* __restrict__ part5,
                                              float* __restrict__ density,
                                              float* __restrict__ distmax, int b0) {
  int g = blockIdx.x * 256 + threadIdx.x;   // bl*N + r
  int bl = g / N, r = g % N;
  int b = b0 + bl;
  const float* base = part5 + (size_t)bl * 48 * 6 * N + r;
  float t5[5] = {FLT_MAX, FLT_MAX, FLT_MAX, FLT_MAX, FLT_MAX};
  float mx = 0.f;
  for (int s = 0; s < 48; ++s) {
    const float* sp = base + (size_t)s * 6 * N;
    ins5b(t5, sp[0]);
    ins5b(t5, sp[(size_t)N]);
    ins5b(t5, sp[2 * (size_t)N]);
    ins5b(t5, sp[3 * (size_t)N]);
    ins5b(t5, sp[4 * (size_t)N]);
    mx = fmaxf(mx, sp[5 * (size_t)N]);
  }
  float sum = t5[0] * t5[0] + t5[1] * t5[1] + t5[2] * t5[2] + t5[3] * t5[3] + t5[4] * t5[4];
  density[b * N + r] = expf(-(sum / 5.0f)) + jax_uniform_bn(b * N + r) * 1e-6f;
  // fused distmax: wave-reduce then one int-atomicMax per wave (dist >= 0 so
  // positive-float bit order == int order). Init done in k_prep.
#pragma unroll
  for (int m = 1; m < 64; m <<= 1) mx = fmaxf(mx, __shfl_xor(mx, m, 64));
  if ((threadIdx.x & 63) == 0) atomicMax((int*)(distmax + b), __float_as_int(mx));
}

// ---------------- masked min -> score (4 rows per wave, 16 per block) ----------------
__global__ __launch_bounds__(256) void k_maskmin(const float* __restrict__ distbuf,
                                                 const float* __restrict__ density,
                                                 const float* __restrict__ distmax,
                                                 float* __restrict__ score, int b0) {
  __shared__ float sd[N];
  int tid = threadIdx.x;
  int wv = tid >> 6, lane = tid & 63;
  int bl = blockIdx.y, b = b0 + bl;
  const float* db = density + (size_t)b * N;
  for (int j = tid * 4; j < N; j += 1024) *(float4*)(sd + j) = *(const float4*)(db + j);
  __syncthreads();
  int i0r = blockIdx.x * 16 + wv * 4;
  float dmax = distmax[b];
  const float* row0 = distbuf + ((size_t)bl * N + i0r) * N;
  float di0 = sd[i0r], di1 = sd[i0r + 1], di2 = sd[i0r + 2], di3 = sd[i0r + 3];
  float mn0 = dmax, mn1 = dmax, mn2 = dmax, mn3 = dmax;
#pragma unroll 2
  for (int it = 0; it < N / 256; ++it) {
    int j = it * 256 + lane * 4;
    float4 d  = *(const float4*)(sd + j);
    float4 v0 = *(const float4*)(row0 + j);
    float4 v1 = *(const float4*)(row0 + (size_t)N + j);
    float4 v2 = *(const float4*)(row0 + 2 * (size_t)N + j);
    float4 v3 = *(const float4*)(row0 + 3 * (size_t)N + j);
    mn0 = fminf(mn0, (d.x > di0) ? v0.x : dmax);
    mn0 = fminf(mn0, (d.y > di0) ? v0.y : dmax);
    mn0 = fminf(mn0, (d.z > di0) ? v0.z : dmax);
    mn0 = fminf(mn0, (d.w > di0) ? v0.w : dmax);
    mn1 = fminf(mn1, (d.x > di1) ? v1.x : dmax);
    mn1 = fminf(mn1, (d.y > di1) ? v1.y : dmax);
    mn1 = fminf(mn1, (d.z > di1) ? v1.z : dmax);
    mn1 = fminf(mn1, (d.w > di1) ? v1.w : dmax);
    mn2 = fminf(mn2, (d.x > di2) ? v2.x : dmax);
    mn2 = fminf(mn2, (d.y > di2) ? v2.y : dmax);
    mn2 = fminf(mn2, (d.z > di2) ? v2.z : dmax);
    mn2 = fminf(mn2, (d.w > di2) ? v2.w : dmax);
    mn3 = fminf(mn3, (d.x > di3) ? v3.x : dmax);
    mn3 = fminf(mn3, (d.y > di3) ? v3.y : dmax);
    mn3 = fminf(mn3, (d.z > di3) ? v3.z : dmax);
    mn3 = fminf(mn3, (d.w > di3) ? v3.w : dmax);
  }
#pragma unroll
  for (int m = 1; m < 64; m <<= 1) {
    mn0 = fminf(mn0, __shfl_xor(mn0, m, 64));
    mn1 = fminf(mn1, __shfl_xor(mn1, m, 64));
    mn2 = fminf(mn2, __shfl_xor(mn2, m, 64));
    mn3 = fminf(mn3, __shfl_xor(mn3, m, 64));
  }
  if (lane == 0) {
    score[b * N + i0r]     = mn0 * di0;
    score[b * N + i0r + 1] = mn1 * di1;
    score[b * N + i0r + 2] = mn2 * di2;
    score[b * N + i0r + 3] = mn3 * di3;
  }
}

// ---------------- counting-rank top-CL (4 rows per wave, 16 per block) ----------------
__global__ __launch_bounds__(256) void k_rank(const float* __restrict__ score,
                                              int* __restrict__ index_down,
                                              int* __restrict__ rank, int b0) {
  __shared__ float ssc[N];
  int tid = threadIdx.x;
  int wv = tid >> 6, lane = tid & 63;
  int b = b0 + blockIdx.y;
  const float* sb = score + (size_t)b * N;
  for (int j = tid * 4; j < N; j += 1024) *(float4*)(ssc + j) = *(const float4*)(sb + j);
  __syncthreads();
  int i0r = blockIdx.x * 16 + wv * 4;
  float s0 = ssc[i0r], s1 = ssc[i0r + 1], s2 = ssc[i0r + 2], s3 = ssc[i0r + 3];
  int c0 = 0, c1 = 0, c2 = 0, c3 = 0;
#pragma unroll 2
  for (int it = 0; it < N / 256; ++it) {
    int j = it * 256 + lane * 4;
    float4 v = *(const float4*)(ssc + j);
    c0 += (v.x > s0) || (v.x == s0 && (j + 0) < i0r);
    c0 += (v.y > s0) || (v.y == s0 && (j + 1) < i0r);
    c0 += (v.z > s0) || (v.z == s0 && (j + 2) < i0r);
    c0 += (v.w > s0) || (v.w == s0 && (j + 3) < i0r);
    c1 += (v.x > s1) || (v.x == s1 && (j + 0) < i0r + 1);
    c1 += (v.y > s1) || (v.y == s1 && (j + 1) < i0r + 1);
    c1 += (v.z > s1) || (v.z == s1 && (j + 2) < i0r + 1);
    c1 += (v.w > s1) || (v.w == s1 && (j + 3) < i0r + 1);
    c2 += (v.x > s2) || (v.x == s2 && (j + 0) < i0r + 2);
    c2 += (v.y > s2) || (v.y == s2 && (j + 1) < i0r + 2);
    c2 += (v.z > s2) || (v.z == s2 && (j + 2) < i0r + 2);
    c2 += (v.w > s2) || (v.w == s2 && (j + 3) < i0r + 2);
    c3 += (v.x > s3) || (v.x == s3 && (j + 0) < i0r + 3);
    c3 += (v.y > s3) || (v.y == s3 && (j + 1) < i0r + 3);
    c3 += (v.z > s3) || (v.z == s3 && (j + 2) < i0r + 3);
    c3 += (v.w > s3) || (v.w == s3 && (j + 3) < i0r + 3);
  }
#pragma unroll
  for (int m = 1; m < 64; m <<= 1) {
    c0 += __shfl_xor(c0, m, 64);
    c1 += __shfl_xor(c1, m, 64);
    c2 += __shfl_xor(c2, m, 64);
    c3 += __shfl_xor(c3, m, 64);
  }
  if (lane == 0) {
    rank[b * N + i0r]     = (c0 < CL) ? c0 : -1;
    rank[b * N + i0r + 1] = (c1 < CL) ? c1 : -1;
    rank[b * N + i0r + 2] = (c2 < CL) ? c2 : -1;
    rank[b * N + i0r + 3] = (c3 < CL) ? c3 : -1;
    if (c0 < CL) index_down[b * CL + c0] = i0r;
    if (c1 < CL) index_down[b * CL + c1] = i0r + 1;
    if (c2 < CL) index_down[b * CL + c2] = i0r + 2;
    if (c3 < CL) index_down[b * CL + c3] = i0r + 3;
  }
}

// ---------------- assignment: chunked center rows + packed atomicMin ----------------
__global__ __launch_bounds__(256) void k_assign_part(const float* __restrict__ distbuf,
                                                     const int* __restrict__ index_down,
                                                     unsigned long long* __restrict__ packed, int b0) {
  constexpr int RCH = CL / 8;  // 96
  __shared__ int sid[RCH];
  int bl = blockIdx.z, b = b0 + bl;
  int r0 = blockIdx.y * RCH;
  int tid = threadIdx.x;
  for (int r = tid; r < RCH; r += 256) sid[r] = index_down[b * CL + r0 + r];
  __syncthreads();
  int j = blockIdx.x * 256 + tid;
  const float* base = distbuf + (size_t)bl * N * N;
  float best = FLT_MAX; int bestr = 0;
#pragma unroll 8
  for (int r = 0; r < RCH; ++r) {
    float d = base[(size_t)sid[r] * N + j];
    if (d < best) { best = d; bestr = r0 + r; }
  }
  unsigned long long key = ((unsigned long long)__float_as_uint(best) << 32) | (unsigned)bestr;
  atomicMin(&packed[b * N + j], key);
}

__global__ void k_assign_fin2(const unsigned long long* __restrict__ packed,
                              const int* __restrict__ rank,
                              int* __restrict__ idx_cluster, int* __restrict__ counts) {
  int g = blockIdx.x * 256 + threadIdx.x;
  int b = g / N;
  int r = rank[g];
  int cl = (r >= 0) ? r : (int)(unsigned)(packed[g] & 0xffffffffull);
  idx_cluster[g] = cl;
  atomicAdd(&counts[b * CL + cl], 1);
}

// ---------------- merge ----------------
__global__ __launch_bounds__(1024) void k_scan(const int* __restrict__ counts,
                                               int* __restrict__ offsets, int* __restrict__ cursor) {
  constexpr int T = B * CL;
  __shared__ int sm[T];
  int tid = threadIdx.x;
  for (int p = tid; p < T; p += 1024) sm[p] = counts[p];
  __syncthreads();
  for (int off = 1; off < T; off <<= 1) {
    int v[3]; int n = 0;
    for (int p = tid; p < T; p += 1024) { v[n++] = (p >= off) ? sm[p - off] : 0; }
    __syncthreads();
    n = 0;
    for (int p = tid; p < T; p += 1024) { sm[p] += v[n++]; }
    __syncthreads();
  }
  for (int p = tid; p < T; p += 1024) {
    int e = sm[p] - counts[p];
    offsets[p] = e; cursor[p] = e;
  }
}

__global__ void k_fill(const int* __restrict__ idx_cluster, int* __restrict__ cursor,
                       int* __restrict__ members) {
  int g = blockIdx.x * 256 + threadIdx.x;
  int b = g / N, i = g % N;
  int seg = b * CL + idx_cluster[g];
  int pos = atomicAdd(&cursor[seg], 1);
  members[pos] = i;
}

__global__ __launch_bounds__(128) void k_gather(const float* __restrict__ x, const int* __restrict__ members,
                                                const int* __restrict__ offsets, const int* __restrict__ counts,
                                                float* __restrict__ out0) {
  int seg = blockIdx.x;
  int b = seg / CL;
  int cnt = counts[seg], off = offsets[seg];
  float nw = 1.0f / ((float)cnt + 1e-6f);
  int c = threadIdx.x * 4;
  const float* xb = x + (size_t)b * N * C;
  float4 acc = make_float4(0.f, 0.f, 0.f, 0.f);
  for (int m = 0; m < cnt; ++m) {
    int tok = members[off + m];
    float4 v = *(const float4*)(xb + (size_t)tok * C + c);
    acc.x += v.x * nw; acc.y += v.y * nw; acc.z += v.z * nw; acc.w += v.w * nw;
  }
  *(float4*)(out0 + (size_t)seg * C + c) = acc;
}

__global__ void k_final(const float* __restrict__ agg_weight, const int* __restrict__ idx_token,
                        const int* __restrict__ idx_cluster, const int* __restrict__ counts,
                        float* __restrict__ out1, float* __restrict__ out2, float* __restrict__ out3) {
  int g = blockIdx.x * 256 + threadIdx.x;
  int b = g / N;
  int it = idx_token[g];
  int clt = idx_cluster[b * N + it];
  float nwt = 1.0f / ((float)counts[b * CL + clt] + 1e-6f);
  out1[g] = agg_weight[g] * nwt;
  out2[g] = (float)clt;
  out3[g] = (float)idx_cluster[g];
}

// ---------------- launch ----------------
extern "C" void kernel_launch(void* const* d_in, const int* in_sizes, int n_in,
                              void* d_out, int out_size, void* d_ws, size_t ws_size,
                              hipStream_t stream) {
  const float* x          = (const float*)d_in[0];
  const int*   idx_token  = (const int*)d_in[1];
  const float* agg_weight = (const float*)d_in[2];

  float* out0 = (float*)d_out;
  float* out1 = out0 + (size_t)B * CL * C;
  float* out2 = out1 + (size_t)B * N;
  float* out3 = out2 + (size_t)B * N;

  char* w = (char*)d_ws;
  auto carve = [&](size_t bytes) { char* p = w; w += (bytes + 255) & ~(size_t)255; return p; };
  float*    sq         = (float*)carve((size_t)B * N * 4);
  float*    density    = (float*)carve((size_t)B * N * 4);
  float*    score      = (float*)carve((size_t)B * N * 4);
  float*    distmax    = (float*)carve((size_t)B * 4);
  int*      index_down = (int*)carve((size_t)B * CL * 4);
  int*      rank       = (int*)carve((size_t)B * N * 4);
  int*      idx_clus   = (int*)carve((size_t)B * N * 4);
  int*      counts     = (int*)carve((size_t)B * CL * 4);
  int*      offsets    = (int*)carve((size_t)B * CL * 4);
  int*      cursor     = (int*)carve((size_t)B * CL * 4);
  int*      members    = (int*)carve((size_t)B * N * 4);
  unsigned long long* packed = (unsigned long long*)carve((size_t)B * N * 8);
  u16*      xhi        = (u16*)carve((size_t)B * N * C * 2);
  u16*      xlo        = (u16*)carve((size_t)B * N * C * 2);
  float*    part5      = (float*)carve((size_t)B * 48 * 6 * N * 4);
  size_t used = (size_t)(w - (char*)d_ws);
  size_t per  = (size_t)N * N * 4;
  int nb_max = (ws_size > used) ? (int)((ws_size - used) / per) : 0;
  if (nb_max < 1) nb_max = 1;
  if (nb_max > B) nb_max = B;
  float* distbuf = (float*)w;

  k_prep<<<B * N, 64, 0, stream>>>(x, sq, xhi, xlo, counts, packed, distmax);

  for (int b0 = 0; b0 < B; b0 += nb_max) {
    int nb = (B - b0 < nb_max) ? (B - b0) : nb_max;
    k_distm<<<dim3(NTILE3, nb), 256, 0, stream>>>(xhi, xlo, sq, distbuf, part5, b0);
    k_dens<<<(nb * N) / 256, 256, 0, stream>>>(part5, density, distmax, b0);
    k_maskmin<<<dim3(N / 16, nb), 256, 0, stream>>>(distbuf, density, distmax, score, b0);
    k_rank<<<dim3(N / 16, nb), 256, 0, stream>>>(score, index_down, rank, b0);
    k_assign_part<<<dim3(N / 256, 8, nb), 256, 0, stream>>>(distbuf, index_down, packed, b0);
  }

  k_assign_fin2<<<(B * N) / 256, 256, 0, stream>>>(packed, rank, idx_clus, counts);
  k_scan<<<1, 1024, 0, stream>>>(counts, offsets, cursor);
  k_fill<<<(B * N) / 256, 256, 0, stream>>>(idx_clus, cursor, members);
  k_gather<<<B * CL, 128, 0, stream>>>(x, members, offsets, counts, out0);
  k_final<<<(B * N) / 256, 256, 0, stream>>>(agg_weight, idx_token, idx_clus, counts, out1, out2, out3);
}

// Round 7
// 291.875 us; speedup vs baseline: 1.3544x; 1.1511x over previous
//
#include <hip/hip_runtime.h>
#include <math.h>
#include <float.h>

constexpr int B  = 4;
constexpr int N  = 3072;
constexpr int C  = 512;
constexpr int CL = 768;

typedef unsigned short u16;
typedef __attribute__((ext_vector_type(8))) short s16x8;
typedef __attribute__((ext_vector_type(4))) float f32x4;

// ---------------- JAX threefry2x32 (exact) ----------------
__device__ __forceinline__ unsigned rotl32(unsigned v, int d) { return (v << d) | (v >> (32 - d)); }

__device__ inline void threefry2x32(unsigned k0, unsigned k1, unsigned c0, unsigned c1,
                                    unsigned& o0, unsigned& o1) {
  unsigned ks0 = k0, ks1 = k1, ks2 = 0x1BD11BDAu ^ k0 ^ k1;
  unsigned x0 = c0 + ks0, x1 = c1 + ks1;
#define TF_RND(r) { x0 += x1; x1 = rotl32(x1, (r)); x1 ^= x0; }
  TF_RND(13) TF_RND(15) TF_RND(26) TF_RND(6)  x0 += ks1; x1 += ks2 + 1u;
  TF_RND(17) TF_RND(29) TF_RND(16) TF_RND(24) x0 += ks2; x1 += ks0 + 2u;
  TF_RND(13) TF_RND(15) TF_RND(26) TF_RND(6)  x0 += ks0; x1 += ks1 + 3u;
  TF_RND(17) TF_RND(29) TF_RND(16) TF_RND(24) x0 += ks1; x1 += ks2 + 4u;
  TF_RND(13) TF_RND(15) TF_RND(26) TF_RND(6)  x0 += ks2; x1 += ks0 + 5u;
#undef TF_RND
  o0 = x0; o1 = x1;
}

__device__ inline float jax_uniform_bn(int f) {
  constexpr int HALF = (B * N) / 2;
  unsigned o0, o1, bits;
  if (f < HALF) { threefry2x32(0u, 42u, (unsigned)f, (unsigned)(f + HALF), o0, o1); bits = o0; }
  else          { threefry2x32(0u, 42u, (unsigned)(f - HALF), (unsigned)f, o0, o1); bits = o1; }
  return __uint_as_float((bits >> 9) | 0x3f800000u) - 1.0f;
}

// ---------------- bf16 split helpers ----------------
__device__ __forceinline__ u16 bf16rn(float f) {
  unsigned u = __float_as_uint(f);
  unsigned r = u + 0x7FFFu + ((u >> 16) & 1u);
  return (u16)(r >> 16);
}
__device__ __forceinline__ float bf16tof(u16 h) {
  return __uint_as_float(((unsigned)h) << 16);
}

// ---------------- prep: sq + hi/lo split + init (one wave per row) ----------------
__global__ __launch_bounds__(64) void k_prep(const float* __restrict__ x, float* __restrict__ sq,
                                             u16* __restrict__ xhi, u16* __restrict__ xlo,
                                             int* __restrict__ counts,
                                             unsigned long long* __restrict__ packed,
                                             float* __restrict__ distmax) {
  int row = blockIdx.x;   // 0..B*N-1
  int lane = threadIdx.x;
  const float* xr = x + (size_t)row * C;
  u16* hr = xhi + (size_t)row * C;
  u16* lr = xlo + (size_t)row * C;
  float s = 0.f;
  for (int c = lane * 4; c < C; c += 256) {
    float4 v = *(const float4*)(xr + c);
    s += v.x * v.x + v.y * v.y + v.z * v.z + v.w * v.w;
    u16 h0 = bf16rn(v.x), h1 = bf16rn(v.y), h2 = bf16rn(v.z), h3 = bf16rn(v.w);
    u16 l0 = bf16rn(v.x - bf16tof(h0));
    u16 l1 = bf16rn(v.y - bf16tof(h1));
    u16 l2 = bf16rn(v.z - bf16tof(h2));
    u16 l3 = bf16rn(v.w - bf16tof(h3));
    uint2 hp, lp;
    hp.x = (unsigned)h0 | ((unsigned)h1 << 16); hp.y = (unsigned)h2 | ((unsigned)h3 << 16);
    lp.x = (unsigned)l0 | ((unsigned)l1 << 16); lp.y = (unsigned)l2 | ((unsigned)l3 << 16);
    *(uint2*)(hr + c) = hp;
    *(uint2*)(lr + c) = lp;
  }
  for (int o = 32; o > 0; o >>= 1) s += __shfl_down(s, o, 64);
  if (lane == 0) {
    sq[row] = s;
    packed[row] = ~0ull;
    if (row < B * CL) counts[row] = 0;
    if (row < B) distmax[row] = 0.f;
  }
}

// ---------------- branchless sorted-insert of v into ascending t[0..4] ----------------
__device__ __forceinline__ void ins5b(float t[5], float v) {
  float c = v;
  float n;
  n = fminf(t[0], c); c = fmaxf(t[0], c); t[0] = n;
  n = fminf(t[1], c); c = fmaxf(t[1], c); t[1] = n;
  n = fminf(t[2], c); c = fmaxf(t[2], c); t[2] = n;
  n = fminf(t[3], c); c = fmaxf(t[3], c); t[3] = n;
  t[4] = fminf(t[4], c);
}

constexpr int NT3 = N / 128;                   // 24
constexpr int NTILE3 = NT3 * (NT3 + 1) / 2;    // 300

// ---------------- dist GEMM (3-term bf16 MFMA), 128x128 tile ----------------
// Round-6 post-mortem: A-in-registers (r4/r6) regressed — the per-lane A
// gather is uncoalesced (16 cache lines per load). REVERT to the round-3
// proven structure (A+B staged via coalesced global_load_lds, 64KB LDS,
// 2 blocks/CU, counted vmcnt(8)) = 96.6us measured.
// Single delta this round: T5 s_setprio(1) around the ds_read+MFMA cluster.
// With 2 independent blocks/CU at unsynchronized phases, the CU scheduler
// can favor MFMA-issuing waves over the other block's staging waves.
__global__ __launch_bounds__(256, 2) void k_distm(const u16* __restrict__ xhi, const u16* __restrict__ xlo,
                                                  const float* __restrict__ sq,
                                                  float* __restrict__ distbuf,
                                                  float* __restrict__ part5, int b0) {
  // layout (u16 units): buf(2) x [ Ah(4096) | Al(4096) | Bh(4096) | Bl(4096) ]
  __shared__ __align__(16) char smem[65536];
  u16* smem_u16 = (u16*)smem;

  int bl = blockIdx.y, b = b0 + bl;

  // bijective XCD swizzle over the 300 tiles of this batch-slice
  int bx = blockIdx.x;
  constexpr int NX = 8, QX = NTILE3 / NX, RX = NTILE3 % NX;  // 37, 4
  int xcd = bx % NX, sub = bx / NX;
  int idx = (xcd < RX ? xcd * (QX + 1) : RX * (QX + 1) + (xcd - RX) * QX) + sub;

  int ti = 0, rem = idx;
  while (rem >= NT3 - ti) { rem -= NT3 - ti; ++ti; }
  int tj = ti + rem;
  int i0 = ti * 128, j0 = tj * 128;
  bool do_mirror = (ti != tj);

  const float* sqb = sq + (size_t)b * N;
  float* dist = distbuf + (size_t)bl * N * N;

  int tid = threadIdx.x;
  int lane = tid & 63, w = tid >> 6;
  int wr = (w >> 1) * 64, wc = (w & 1) * 64;
  int l15 = lane & 15, l4 = lane >> 4;
  int csw = (lane >> 1) & 3;           // read-side chunk swizzle (row bits 1-2)

  // per-wave staging source: wave 0->Ah, 1->Al, 2->Bh, 3->Bl.
  // each wave loads 8 chunks of 16 rows x 32 u16 (1KB) per K-step.
  // global source chunk is pre-swizzled: chunk ^= (row>>1)&3 == (lane>>3)&3.
  const u16* hil = (w & 1) ? xlo : xhi;
  int rbase0 = (w < 2) ? i0 : j0;
  const u16* gsrc = hil + ((size_t)b * N + rbase0 + (lane >> 2)) * C
                        + ((lane & 3) ^ ((lane >> 3) & 3)) * 8;

  f32x4 acc[4][4];
#pragma unroll
  for (int rt = 0; rt < 4; ++rt)
#pragma unroll
    for (int ct = 0; ct < 4; ++ct)
#pragma unroll
      for (int e = 0; e < 4; ++e) acc[rt][ct][e] = 0.f;

  // prologue: stage buf0 at k=0 (no wait here; first KSTEP waits vmcnt(8))
  {
    u16* lb = smem_u16 + w * 4096;
#pragma unroll
    for (int q = 0; q < 8; ++q)
      __builtin_amdgcn_global_load_lds(
          (const __attribute__((address_space(1))) void*)(gsrc + q * 16 * C),
          (__attribute__((address_space(3))) void*)(lb + q * 512), 16, 0, 0);
  }

#define KSTEP(CUR, STG, KNXT, DO_STAGE)                                              \
  {                                                                                  \
    if (DO_STAGE) {                                                                  \
      u16* lb = smem_u16 + (STG) * 16384 + w * 4096;                                 \
      const u16* gs = gsrc + (KNXT);                                                 \
      _Pragma("unroll")                                                              \
      for (int q = 0; q < 8; ++q)                                                    \
        __builtin_amdgcn_global_load_lds(                                            \
            (const __attribute__((address_space(1))) void*)(gs + q * 16 * C),        \
            (__attribute__((address_space(3))) void*)(lb + q * 512), 16, 0, 0);      \
      asm volatile("s_waitcnt vmcnt(8)" ::: "memory");                               \
    } else {                                                                         \
      asm volatile("s_waitcnt vmcnt(0)" ::: "memory");                               \
    }                                                                                \
    __builtin_amdgcn_s_barrier();                                                    \
    asm volatile("" ::: "memory");                                                   \
    __builtin_amdgcn_s_setprio(1);                                                   \
    const u16* sb = smem_u16 + (CUR) * 16384;                                        \
    s16x8 ah[4], al[4];                                                              \
    _Pragma("unroll")                                                                \
    for (int rt = 0; rt < 4; ++rt) {                                                 \
      int ro = (wr + rt * 16 + l15) * 32 + (l4 ^ csw) * 8;                           \
      ah[rt] = *(const s16x8*)(sb + ro);                                             \
      al[rt] = *(const s16x8*)(sb + 4096 + ro);                                      \
    }                                                                                \
    _Pragma("unroll")                                                                \
    for (int ct = 0; ct < 4; ++ct) {                                                 \
      int co = (wc + ct * 16 + l15) * 32 + (l4 ^ csw) * 8;                           \
      s16x8 bh = *(const s16x8*)(sb + 8192 + co);                                    \
      s16x8 bl = *(const s16x8*)(sb + 12288 + co);                                   \
      _Pragma("unroll")                                                              \
      for (int rt = 0; rt < 4; ++rt) {                                               \
        acc[rt][ct] = __builtin_amdgcn_mfma_f32_16x16x32_bf16(ah[rt], bh, acc[rt][ct], 0, 0, 0); \
        acc[rt][ct] = __builtin_amdgcn_mfma_f32_16x16x32_bf16(ah[rt], bl, acc[rt][ct], 0, 0, 0); \
        acc[rt][ct] = __builtin_amdgcn_mfma_f32_16x16x32_bf16(al[rt], bh, acc[rt][ct], 0, 0, 0); \
      }                                                                              \
    }                                                                                \
    __builtin_amdgcn_s_setprio(0);                                                   \
    asm volatile("" ::: "memory");                                                   \
    __builtin_amdgcn_s_barrier();                                                    \
    asm volatile("" ::: "memory");                                                   \
  }

  for (int ks = 0; ks < 16; ks += 2) {
    KSTEP(0, 1, (ks + 1) * 32, true)
    KSTEP(1, 0, (ks + 2) * 32, (ks + 2 < 16))
  }
#undef KSTEP

  const float SQC = 22.627416997969522f;
  float sqi[4][4], sqj[4];
#pragma unroll
  for (int rt = 0; rt < 4; ++rt)
#pragma unroll
    for (int r = 0; r < 4; ++r) sqi[rt][r] = sqb[i0 + wr + rt * 16 + l4 * 4 + r];
#pragma unroll
  for (int ct = 0; ct < 4; ++ct) sqj[ct] = sqb[j0 + wc + ct * 16 + l15];

#pragma unroll
  for (int rt = 0; rt < 4; ++rt)
#pragma unroll
    for (int ct = 0; ct < 4; ++ct)
#pragma unroll
      for (int r = 0; r < 4; ++r) {
        float d2 = fmaxf(sqi[rt][r] + sqj[ct] - 2.0f * acc[rt][ct][r], 0.0f);
        acc[rt][ct][r] = sqrtf(d2) / SQC;
      }

  // ---- epilogue: per-wave LDS transpose (32-col passes):
  //  (a) coalesced float4 direct + mirror dist writes
  //  (b) per-row 5-NN partials
  constexpr int TSTR = 77;   // odd dword stride: column scans are conflict-free
  float* sT = (float*)smem + w * (32 * TSTR);

  float t5A[5] = {FLT_MAX, FLT_MAX, FLT_MAX, FLT_MAX, FLT_MAX};
  float mxA = 0.f;

#pragma unroll
  for (int p = 0; p < 2; ++p) {
#pragma unroll
    for (int cth = 0; cth < 2; ++cth) {
      int ct = p * 2 + cth;
      int cl = cth * 16 + l15;
#pragma unroll
      for (int rt = 0; rt < 4; ++rt)
#pragma unroll
        for (int r = 0; r < 4; ++r)
          sT[cl * TSTR + rt * 16 + l4 * 4 + r] = acc[rt][ct][r];
    }
    // direct write
    {
      int g4 = lane & 7, rbase = lane >> 3;
#pragma unroll
      for (int it = 0; it < 8; ++it) {
        int rl = it * 8 + rbase;
        float4 v = make_float4(sT[(4 * g4 + 0) * TSTR + rl],
                               sT[(4 * g4 + 1) * TSTR + rl],
                               sT[(4 * g4 + 2) * TSTR + rl],
                               sT[(4 * g4 + 3) * TSTR + rl]);
        *(float4*)(dist + (size_t)(i0 + wr + rl) * N + j0 + wc + p * 32 + 4 * g4) = v;
      }
    }
    // mirror write (scalar LDS reads: TSTR=77 breaks float4 alignment, and
    // the scalar pattern is <=2-way on banks)
    if (do_mirror) {
      int cg = lane >> 4, rq = lane & 15;
#pragma unroll
      for (int cc = 0; cc < 8; ++cc) {
        int c = cc * 4 + cg;
        float4 v;
        v.x = sT[c * TSTR + rq * 4 + 0];
        v.y = sT[c * TSTR + rq * 4 + 1];
        v.z = sT[c * TSTR + rq * 4 + 2];
        v.w = sT[c * TSTR + rq * 4 + 3];
        *(float4*)(dist + (size_t)(j0 + wc + p * 32 + c) * N + i0 + wr + rq * 4) = v;
      }
    }
    // (b1) A-side partial scan
    for (int c = 0; c < 32; ++c) {
      float v = sT[c * TSTR + lane];
      mxA = fmaxf(mxA, v);
      ins5b(t5A, v);
    }
    // (b2) mirror-side partials
    if (do_mirror) {
      int cl = lane & 31, half = lane >> 5;
      float t5B[5] = {FLT_MAX, FLT_MAX, FLT_MAX, FLT_MAX, FLT_MAX};
      float mxB = 0.f;
      for (int k = 0; k < 32; ++k) {
        float v = sT[cl * TSTR + half * 32 + k];
        mxB = fmaxf(mxB, v);
        ins5b(t5B, v);
      }
      mxB = fmaxf(mxB, __shfl_xor(mxB, 32, 64));
      float o0 = __shfl_xor(t5B[0], 32, 64);
      float o1 = __shfl_xor(t5B[1], 32, 64);
      float o2 = __shfl_xor(t5B[2], 32, 64);
      float o3 = __shfl_xor(t5B[3], 32, 64);
      float o4 = __shfl_xor(t5B[4], 32, 64);
      ins5b(t5B, o0); ins5b(t5B, o1); ins5b(t5B, o2); ins5b(t5B, o3); ins5b(t5B, o4);
      if (half == 0) {
        int rowB = j0 + wc + p * 32 + cl;
        int slotB = ti * 2 + (wr >> 6);
        float* dst = part5 + (((size_t)bl * 48 + slotB) * 6) * N + rowB;
        dst[0] = t5B[0]; dst[(size_t)N] = t5B[1]; dst[2 * (size_t)N] = t5B[2];
        dst[3 * (size_t)N] = t5B[3]; dst[4 * (size_t)N] = t5B[4]; dst[5 * (size_t)N] = mxB;
      }
    }
  }
  {
    int rowA = i0 + wr + lane;
    int slotA = tj * 2 + (wc >> 6);
    float* dst = part5 + (((size_t)bl * 48 + slotA) * 6) * N + rowA;
    dst[0] = t5A[0]; dst[(size_t)N] = t5A[1]; dst[2 * (size_t)N] = t5A[2];
    dst[3 * (size_t)N] = t5A[3]; dst[4 * (size_t)N] = t5A[4]; dst[5 * (size_t)N] = mxA;
  }
}

// ---------------- density from 48-slot partials (+ fused distmax atomicMax) ----------------
__global__ __launch_bounds__(256) void k_dens(const float* __restrict__ part5,
                                              float* __restrict__ density,
                                              float* __restrict__ distmax, int b0) {
  int g = blockIdx.x * 256 + threadIdx.x;   // bl*N + r
  int bl = g / N, r = g % N;
  int b = b0 + bl;
  const float* base = part5 + (size_t)bl * 48 * 6 * N + r;
  float t5[5] = {FLT_MAX, FLT_MAX, FLT_MAX, FLT_MAX, FLT_MAX};
  float mx = 0.f;
  for (int s = 0; s < 48; ++s) {
    const float* sp = base + (size_t)s * 6 * N;
    ins5b(t5, sp[0]);
    ins5b(t5, sp[(size_t)N]);
    ins5b(t5, sp[2 * (size_t)N]);
    ins5b(t5, sp[3 * (size_t)N]);
    ins5b(t5, sp[4 * (size_t)N]);
    mx = fmaxf(mx, sp[5 * (size_t)N]);
  }
  float sum = t5[0] * t5[0] + t5[1] * t5[1] + t5[2] * t5[2] + t5[3] * t5[3] + t5[4] * t5[4];
  density[b * N + r] = expf(-(sum / 5.0f)) + jax_uniform_bn(b * N + r) * 1e-6f;
  // fused distmax: wave-reduce then one int-atomicMax per wave (dist >= 0 so
  // positive-float bit order == int order). Init done in k_prep.
#pragma unroll
  for (int m = 1; m < 64; m <<= 1) mx = fmaxf(mx, __shfl_xor(mx, m, 64));
  if ((threadIdx.x & 63) == 0) atomicMax((int*)(distmax + b), __float_as_int(mx));
}

// ---------------- masked min -> score (4 rows per wave, 16 per block) ----------------
__global__ __launch_bounds__(256) void k_maskmin(const float* __restrict__ distbuf,
                                                 const float* __restrict__ density,
                                                 const float* __restrict__ distmax,
                                                 float* __restrict__ score, int b0) {
  __shared__ float sd[N];
  int tid = threadIdx.x;
  int wv = tid >> 6, lane = tid & 63;
  int bl = blockIdx.y, b = b0 + bl;
  const float* db = density + (size_t)b * N;
  for (int j = tid * 4; j < N; j += 1024) *(float4*)(sd + j) = *(const float4*)(db + j);
  __syncthreads();
  int i0r = blockIdx.x * 16 + wv * 4;
  float dmax = distmax[b];
  const float* row0 = distbuf + ((size_t)bl * N + i0r) * N;
  float di0 = sd[i0r], di1 = sd[i0r + 1], di2 = sd[i0r + 2], di3 = sd[i0r + 3];
  float mn0 = dmax, mn1 = dmax, mn2 = dmax, mn3 = dmax;
#pragma unroll 2
  for (int it = 0; it < N / 256; ++it) {
    int j = it * 256 + lane * 4;
    float4 d  = *(const float4*)(sd + j);
    float4 v0 = *(const float4*)(row0 + j);
    float4 v1 = *(const float4*)(row0 + (size_t)N + j);
    float4 v2 = *(const float4*)(row0 + 2 * (size_t)N + j);
    float4 v3 = *(const float4*)(row0 + 3 * (size_t)N + j);
    mn0 = fminf(mn0, (d.x > di0) ? v0.x : dmax);
    mn0 = fminf(mn0, (d.y > di0) ? v0.y : dmax);
    mn0 = fminf(mn0, (d.z > di0) ? v0.z : dmax);
    mn0 = fminf(mn0, (d.w > di0) ? v0.w : dmax);
    mn1 = fminf(mn1, (d.x > di1) ? v1.x : dmax);
    mn1 = fminf(mn1, (d.y > di1) ? v1.y : dmax);
    mn1 = fminf(mn1, (d.z > di1) ? v1.z : dmax);
    mn1 = fminf(mn1, (d.w > di1) ? v1.w : dmax);
    mn2 = fminf(mn2, (d.x > di2) ? v2.x : dmax);
    mn2 = fminf(mn2, (d.y > di2) ? v2.y : dmax);
    mn2 = fminf(mn2, (d.z > di2) ? v2.z : dmax);
    mn2 = fminf(mn2, (d.w > di2) ? v2.w : dmax);
    mn3 = fminf(mn3, (d.x > di3) ? v3.x : dmax);
    mn3 = fminf(mn3, (d.y > di3) ? v3.y : dmax);
    mn3 = fminf(mn3, (d.z > di3) ? v3.z : dmax);
    mn3 = fminf(mn3, (d.w > di3) ? v3.w : dmax);
  }
#pragma unroll
  for (int m = 1; m < 64; m <<= 1) {
    mn0 = fminf(mn0, __shfl_xor(mn0, m, 64));
    mn1 = fminf(mn1, __shfl_xor(mn1, m, 64));
    mn2 = fminf(mn2, __shfl_xor(mn2, m, 64));
    mn3 = fminf(mn3, __shfl_xor(mn3, m, 64));
  }
  if (lane == 0) {
    score[b * N + i0r]     = mn0 * di0;
    score[b * N + i0r + 1] = mn1 * di1;
    score[b * N + i0r + 2] = mn2 * di2;
    score[b * N + i0r + 3] = mn3 * di3;
  }
}

// ---------------- counting-rank top-CL (4 rows per wave, 16 per block) ----------------
__global__ __launch_bounds__(256) void k_rank(const float* __restrict__ score,
                                              int* __restrict__ index_down,
                                              int* __restrict__ rank, int b0) {
  __shared__ float ssc[N];
  int tid = threadIdx.x;
  int wv = tid >> 6, lane = tid & 63;
  int b = b0 + blockIdx.y;
  const float* sb = score + (size_t)b * N;
  for (int j = tid * 4; j < N; j += 1024) *(float4*)(ssc + j) = *(const float4*)(sb + j);
  __syncthreads();
  int i0r = blockIdx.x * 16 + wv * 4;
  float s0 = ssc[i0r], s1 = ssc[i0r + 1], s2 = ssc[i0r + 2], s3 = ssc[i0r + 3];
  int c0 = 0, c1 = 0, c2 = 0, c3 = 0;
#pragma unroll 2
  for (int it = 0; it < N / 256; ++it) {
    int j = it * 256 + lane * 4;
    float4 v = *(const float4*)(ssc + j);
    c0 += (v.x > s0) || (v.x == s0 && (j + 0) < i0r);
    c0 += (v.y > s0) || (v.y == s0 && (j + 1) < i0r);
    c0 += (v.z > s0) || (v.z == s0 && (j + 2) < i0r);
    c0 += (v.w > s0) || (v.w == s0 && (j + 3) < i0r);
    c1 += (v.x > s1) || (v.x == s1 && (j + 0) < i0r + 1);
    c1 += (v.y > s1) || (v.y == s1 && (j + 1) < i0r + 1);
    c1 += (v.z > s1) || (v.z == s1 && (j + 2) < i0r + 1);
    c1 += (v.w > s1) || (v.w == s1 && (j + 3) < i0r + 1);
    c2 += (v.x > s2) || (v.x == s2 && (j + 0) < i0r + 2);
    c2 += (v.y > s2) || (v.y == s2 && (j + 1) < i0r + 2);
    c2 += (v.z > s2) || (v.z == s2 && (j + 2) < i0r + 2);
    c2 += (v.w > s2) || (v.w == s2 && (j + 3) < i0r + 2);
    c3 += (v.x > s3) || (v.x == s3 && (j + 0) < i0r + 3);
    c3 += (v.y > s3) || (v.y == s3 && (j + 1) < i0r + 3);
    c3 += (v.z > s3) || (v.z == s3 && (j + 2) < i0r + 3);
    c3 += (v.w > s3) || (v.w == s3 && (j + 3) < i0r + 3);
  }
#pragma unroll
  for (int m = 1; m < 64; m <<= 1) {
    c0 += __shfl_xor(c0, m, 64);
    c1 += __shfl_xor(c1, m, 64);
    c2 += __shfl_xor(c2, m, 64);
    c3 += __shfl_xor(c3, m, 64);
  }
  if (lane == 0) {
    rank[b * N + i0r]     = (c0 < CL) ? c0 : -1;
    rank[b * N + i0r + 1] = (c1 < CL) ? c1 : -1;
    rank[b * N + i0r + 2] = (c2 < CL) ? c2 : -1;
    rank[b * N + i0r + 3] = (c3 < CL) ? c3 : -1;
    if (c0 < CL) index_down[b * CL + c0] = i0r;
    if (c1 < CL) index_down[b * CL + c1] = i0r + 1;
    if (c2 < CL) index_down[b * CL + c2] = i0r + 2;
    if (c3 < CL) index_down[b * CL + c3] = i0r + 3;
  }
}

// ---------------- assignment: chunked center rows + packed atomicMin ----------------
__global__ __launch_bounds__(256) void k_assign_part(const float* __restrict__ distbuf,
                                                     const int* __restrict__ index_down,
                                                     unsigned long long* __restrict__ packed, int b0) {
  constexpr int RCH = CL / 8;  // 96
  __shared__ int sid[RCH];
  int bl = blockIdx.z, b = b0 + bl;
  int r0 = blockIdx.y * RCH;
  int tid = threadIdx.x;
  for (int r = tid; r < RCH; r += 256) sid[r] = index_down[b * CL + r0 + r];
  __syncthreads();
  int j = blockIdx.x * 256 + tid;
  const float* base = distbuf + (size_t)bl * N * N;
  float best = FLT_MAX; int bestr = 0;
#pragma unroll 8
  for (int r = 0; r < RCH; ++r) {
    float d = base[(size_t)sid[r] * N + j];
    if (d < best) { best = d; bestr = r0 + r; }
  }
  unsigned long long key = ((unsigned long long)__float_as_uint(best) << 32) | (unsigned)bestr;
  atomicMin(&packed[b * N + j], key);
}

__global__ void k_assign_fin2(const unsigned long long* __restrict__ packed,
                              const int* __restrict__ rank,
                              int* __restrict__ idx_cluster, int* __restrict__ counts) {
  int g = blockIdx.x * 256 + threadIdx.x;
  int b = g / N;
  int r = rank[g];
  int cl = (r >= 0) ? r : (int)(unsigned)(packed[g] & 0xffffffffull);
  idx_cluster[g] = cl;
  atomicAdd(&counts[b * CL + cl], 1);
}

// ---------------- merge ----------------
__global__ __launch_bounds__(1024) void k_scan(const int* __restrict__ counts,
                                               int* __restrict__ offsets, int* __restrict__ cursor) {
  constexpr int T = B * CL;
  __shared__ int sm[T];
  int tid = threadIdx.x;
  for (int p = tid; p < T; p += 1024) sm[p] = counts[p];
  __syncthreads();
  for (int off = 1; off < T; off <<= 1) {
    int v[3]; int n = 0;
    for (int p = tid; p < T; p += 1024) { v[n++] = (p >= off) ? sm[p - off] : 0; }
    __syncthreads();
    n = 0;
    for (int p = tid; p < T; p += 1024) { sm[p] += v[n++]; }
    __syncthreads();
  }
  for (int p = tid; p < T; p += 1024) {
    int e = sm[p] - counts[p];
    offsets[p] = e; cursor[p] = e;
  }
}

__global__ void k_fill(const int* __restrict__ idx_cluster, int* __restrict__ cursor,
                       int* __restrict__ members) {
  int g = blockIdx.x * 256 + threadIdx.x;
  int b = g / N, i = g % N;
  int seg = b * CL + idx_cluster[g];
  int pos = atomicAdd(&cursor[seg], 1);
  members[pos] = i;
}

__global__ __launch_bounds__(128) void k_gather(const float* __restrict__ x, const int* __restrict__ members,
                                                const int* __restrict__ offsets, const int* __restrict__ counts,
                                                float* __restrict__ out0) {
  int seg = blockIdx.x;
  int b = seg / CL;
  int cnt = counts[seg], off = offsets[seg];
  float nw = 1.0f / ((float)cnt + 1e-6f);
  int c = threadIdx.x * 4;
  const float* xb = x + (size_t)b * N * C;
  float4 acc = make_float4(0.f, 0.f, 0.f, 0.f);
  for (int m = 0; m < cnt; ++m) {
    int tok = members[off + m];
    float4 v = *(const float4*)(xb + (size_t)tok * C + c);
    acc.x += v.x * nw; acc.y += v.y * nw; acc.z += v.z * nw; acc.w += v.w * nw;
  }
  *(float4*)(out0 + (size_t)seg * C + c) = acc;
}

__global__ void k_final(const float* __restrict__ agg_weight, const int* __restrict__ idx_token,
                        const int* __restrict__ idx_cluster, const int* __restrict__ counts,
                        float* __restrict__ out1, float* __restrict__ out2, float* __restrict__ out3) {
  int g = blockIdx.x * 256 + threadIdx.x;
  int b = g / N;
  int it = idx_token[g];
  int clt = idx_cluster[b * N + it];
  float nwt = 1.0f / ((float)counts[b * CL + clt] + 1e-6f);
  out1[g] = agg_weight[g] * nwt;
  out2[g] = (float)clt;
  out3[g] = (float)idx_cluster[g];
}

// ---------------- launch ----------------
extern "C" void kernel_launch(void* const* d_in, const int* in_sizes, int n_in,
                              void* d_out, int out_size, void* d_ws, size_t ws_size,
                              hipStream_t stream) {
  const float* x          = (const float*)d_in[0];
  const int*   idx_token  = (const int*)d_in[1];
  const float* agg_weight = (const float*)d_in[2];

  float* out0 = (float*)d_out;
  float* out1 = out0 + (size_t)B * CL * C;
  float* out2 = out1 + (size_t)B * N;
  float* out3 = out2 + (size_t)B * N;

  char* w = (char*)d_ws;
  auto carve = [&](size_t bytes) { char* p = w; w += (bytes + 255) & ~(size_t)255; return p; };
  float*    sq         = (float*)carve((size_t)B * N * 4);
  float*    density    = (float*)carve((size_t)B * N * 4);
  float*    score      = (float*)carve((size_t)B * N * 4);
  float*    distmax    = (float*)carve((size_t)B * 4);
  int*      index_down = (int*)carve((size_t)B * CL * 4);
  int*      rank       = (int*)carve((size_t)B * N * 4);
  int*      idx_clus   = (int*)carve((size_t)B * N * 4);
  int*      counts     = (int*)carve((size_t)B * CL * 4);
  int*      offsets    = (int*)carve((size_t)B * CL * 4);
  int*      cursor     = (int*)carve((size_t)B * CL * 4);
  int*      members    = (int*)carve((size_t)B * N * 4);
  unsigned long long* packed = (unsigned long long*)carve((size_t)B * N * 8);
  u16*      xhi        = (u16*)carve((size_t)B * N * C * 2);
  u16*      xlo        = (u16*)carve((size_t)B * N * C * 2);
  float*    part5      = (float*)carve((size_t)B * 48 * 6 * N * 4);
  size_t used = (size_t)(w - (char*)d_ws);
  size_t per  = (size_t)N * N * 4;
  int nb_max = (ws_size > used) ? (int)((ws_size - used) / per) : 0;
  if (nb_max < 1) nb_max = 1;
  if (nb_max > B) nb_max = B;
  float* distbuf = (float*)w;

  k_prep<<<B * N, 64, 0, stream>>>(x, sq, xhi, xlo, counts, packed, distmax);

  for (int b0 = 0; b0 < B; b0 += nb_max) {
    int nb = (B - b0 < nb_max) ? (B - b0) : nb_max;
    k_distm<<<dim3(NTILE3, nb), 256, 0, stream>>>(xhi, xlo, sq, distbuf, part5, b0);
    k_dens<<<(nb * N) / 256, 256, 0, stream>>>(part5, density, distmax, b0);
    k_maskmin<<<dim3(N / 16, nb), 256, 0, stream>>>(distbuf, density, distmax, score, b0);
    k_rank<<<dim3(N / 16, nb), 256, 0, stream>>>(score, index_down, rank, b0);
    k_assign_part<<<dim3(N / 256, 8, nb), 256, 0, stream>>>(distbuf, index_down, packed, b0);
  }

  k_assign_fin2<<<(B * N) / 256, 256, 0, stream>>>(packed, rank, idx_clus, counts);
  k_scan<<<1, 1024, 0, stream>>>(counts, offsets, cursor);
  k_fill<<<(B * N) / 256, 256, 0, stream>>>(idx_clus, cursor, members);
  k_gather<<<B * CL, 128, 0, stream>>>(x, members, offsets, counts, out0);
  k_final<<<(B * N) / 256, 256, 0, stream>>>(agg_weight, idx_token, idx_clus, counts, out1, out2, out3);
}

// Round 8
// 277.241 us; speedup vs baseline: 1.4259x; 1.0528x over previous
//
#include <hip/hip_runtime.h>
#include <math.h>
#include <float.h>

constexpr int B  = 4;
constexpr int N  = 3072;
constexpr int C  = 512;
constexpr int CL = 768;

typedef unsigned short u16;
typedef __attribute__((ext_vector_type(8))) short s16x8;
typedef __attribute__((ext_vector_type(4))) float f32x4;

// ---------------- JAX threefry2x32 (exact) ----------------
__device__ __forceinline__ unsigned rotl32(unsigned v, int d) { return (v << d) | (v >> (32 - d)); }

__device__ inline void threefry2x32(unsigned k0, unsigned k1, unsigned c0, unsigned c1,
                                    unsigned& o0, unsigned& o1) {
  unsigned ks0 = k0, ks1 = k1, ks2 = 0x1BD11BDAu ^ k0 ^ k1;
  unsigned x0 = c0 + ks0, x1 = c1 + ks1;
#define TF_RND(r) { x0 += x1; x1 = rotl32(x1, (r)); x1 ^= x0; }
  TF_RND(13) TF_RND(15) TF_RND(26) TF_RND(6)  x0 += ks1; x1 += ks2 + 1u;
  TF_RND(17) TF_RND(29) TF_RND(16) TF_RND(24) x0 += ks2; x1 += ks0 + 2u;
  TF_RND(13) TF_RND(15) TF_RND(26) TF_RND(6)  x0 += ks0; x1 += ks1 + 3u;
  TF_RND(17) TF_RND(29) TF_RND(16) TF_RND(24) x0 += ks1; x1 += ks2 + 4u;
  TF_RND(13) TF_RND(15) TF_RND(26) TF_RND(6)  x0 += ks2; x1 += ks0 + 5u;
#undef TF_RND
  o0 = x0; o1 = x1;
}

__device__ inline float jax_uniform_bn(int f) {
  constexpr int HALF = (B * N) / 2;
  unsigned o0, o1, bits;
  if (f < HALF) { threefry2x32(0u, 42u, (unsigned)f, (unsigned)(f + HALF), o0, o1); bits = o0; }
  else          { threefry2x32(0u, 42u, (unsigned)(f - HALF), (unsigned)f, o0, o1); bits = o1; }
  return __uint_as_float((bits >> 9) | 0x3f800000u) - 1.0f;
}

// ---------------- bf16 split helpers ----------------
__device__ __forceinline__ u16 bf16rn(float f) {
  unsigned u = __float_as_uint(f);
  unsigned r = u + 0x7FFFu + ((u >> 16) & 1u);
  return (u16)(r >> 16);
}
__device__ __forceinline__ float bf16tof(u16 h) {
  return __uint_as_float(((unsigned)h) << 16);
}

// ---------------- prep: sq + hi/lo split + init (one wave per row) ----------------
__global__ __launch_bounds__(64) void k_prep(const float* __restrict__ x, float* __restrict__ sq,
                                             u16* __restrict__ xhi, u16* __restrict__ xlo,
                                             int* __restrict__ counts,
                                             unsigned long long* __restrict__ packed,
                                             float* __restrict__ distmax) {
  int row = blockIdx.x;   // 0..B*N-1
  int lane = threadIdx.x;
  const float* xr = x + (size_t)row * C;
  u16* hr = xhi + (size_t)row * C;
  u16* lr = xlo + (size_t)row * C;
  float s = 0.f;
  for (int c = lane * 4; c < C; c += 256) {
    float4 v = *(const float4*)(xr + c);
    s += v.x * v.x + v.y * v.y + v.z * v.z + v.w * v.w;
    u16 h0 = bf16rn(v.x), h1 = bf16rn(v.y), h2 = bf16rn(v.z), h3 = bf16rn(v.w);
    u16 l0 = bf16rn(v.x - bf16tof(h0));
    u16 l1 = bf16rn(v.y - bf16tof(h1));
    u16 l2 = bf16rn(v.z - bf16tof(h2));
    u16 l3 = bf16rn(v.w - bf16tof(h3));
    uint2 hp, lp;
    hp.x = (unsigned)h0 | ((unsigned)h1 << 16); hp.y = (unsigned)h2 | ((unsigned)h3 << 16);
    lp.x = (unsigned)l0 | ((unsigned)l1 << 16); lp.y = (unsigned)l2 | ((unsigned)l3 << 16);
    *(uint2*)(hr + c) = hp;
    *(uint2*)(lr + c) = lp;
  }
  for (int o = 32; o > 0; o >>= 1) s += __shfl_down(s, o, 64);
  if (lane == 0) {
    sq[row] = s;
    packed[row] = ~0ull;
    if (row < B * CL) counts[row] = 0;
    if (row < B) distmax[row] = 0.f;
  }
}

// ---------------- branchless sorted-insert of v into ascending t[0..4] ----------------
__device__ __forceinline__ void ins5b(float t[5], float v) {
  float c = v;
  float n;
  n = fminf(t[0], c); c = fmaxf(t[0], c); t[0] = n;
  n = fminf(t[1], c); c = fmaxf(t[1], c); t[1] = n;
  n = fminf(t[2], c); c = fmaxf(t[2], c); t[2] = n;
  n = fminf(t[3], c); c = fmaxf(t[3], c); t[3] = n;
  t[4] = fminf(t[4], c);
}

constexpr int NT3 = N / 128;                   // 24
constexpr int NTILE3 = NT3 * (NT3 + 1) / 2;    // 300

// ---------------- dist GEMM (3-term bf16 MFMA), 128x128 tile ----------------
// Round-7 post-mortem: setprio bought <=1.4us (T5-null on 2-phase lockstep,
// matches m190) AND the r7 profile contained a pathological 31ms dispatch —
// removed. This is the exact round-3 structure (best verified: 96.6us):
// A+B staged via coalesced global_load_lds, 64KB LDS double buffer,
// source-side chunk XOR-swizzle, counted vmcnt(8), 2 barriers/K-step.
__global__ __launch_bounds__(256, 2) void k_distm(const u16* __restrict__ xhi, const u16* __restrict__ xlo,
                                                  const float* __restrict__ sq,
                                                  float* __restrict__ distbuf,
                                                  float* __restrict__ part5, int b0) {
  // layout (u16 units): buf(2) x [ Ah(4096) | Al(4096) | Bh(4096) | Bl(4096) ]
  __shared__ __align__(16) char smem[65536];
  u16* smem_u16 = (u16*)smem;

  int bl = blockIdx.y, b = b0 + bl;

  // bijective XCD swizzle over the 300 tiles of this batch-slice
  int bx = blockIdx.x;
  constexpr int NX = 8, QX = NTILE3 / NX, RX = NTILE3 % NX;  // 37, 4
  int xcd = bx % NX, sub = bx / NX;
  int idx = (xcd < RX ? xcd * (QX + 1) : RX * (QX + 1) + (xcd - RX) * QX) + sub;

  int ti = 0, rem = idx;
  while (rem >= NT3 - ti) { rem -= NT3 - ti; ++ti; }
  int tj = ti + rem;
  int i0 = ti * 128, j0 = tj * 128;
  bool do_mirror = (ti != tj);

  const float* sqb = sq + (size_t)b * N;
  float* dist = distbuf + (size_t)bl * N * N;

  int tid = threadIdx.x;
  int lane = tid & 63, w = tid >> 6;
  int wr = (w >> 1) * 64, wc = (w & 1) * 64;
  int l15 = lane & 15, l4 = lane >> 4;
  int csw = (lane >> 1) & 3;           // read-side chunk swizzle (row bits 1-2)

  // per-wave staging source: wave 0->Ah, 1->Al, 2->Bh, 3->Bl.
  // each wave loads 8 chunks of 16 rows x 32 u16 (1KB) per K-step.
  // global source chunk is pre-swizzled: chunk ^= (row>>1)&3 == (lane>>3)&3.
  const u16* hil = (w & 1) ? xlo : xhi;
  int rbase0 = (w < 2) ? i0 : j0;
  const u16* gsrc = hil + ((size_t)b * N + rbase0 + (lane >> 2)) * C
                        + ((lane & 3) ^ ((lane >> 3) & 3)) * 8;

  f32x4 acc[4][4];
#pragma unroll
  for (int rt = 0; rt < 4; ++rt)
#pragma unroll
    for (int ct = 0; ct < 4; ++ct)
#pragma unroll
      for (int e = 0; e < 4; ++e) acc[rt][ct][e] = 0.f;

  // prologue: stage buf0 at k=0 (no wait here; first KSTEP waits vmcnt(8))
  {
    u16* lb = smem_u16 + w * 4096;
#pragma unroll
    for (int q = 0; q < 8; ++q)
      __builtin_amdgcn_global_load_lds(
          (const __attribute__((address_space(1))) void*)(gsrc + q * 16 * C),
          (__attribute__((address_space(3))) void*)(lb + q * 512), 16, 0, 0);
  }

#define KSTEP(CUR, STG, KNXT, DO_STAGE)                                              \
  {                                                                                  \
    if (DO_STAGE) {                                                                  \
      u16* lb = smem_u16 + (STG) * 16384 + w * 4096;                                 \
      const u16* gs = gsrc + (KNXT);                                                 \
      _Pragma("unroll")                                                              \
      for (int q = 0; q < 8; ++q)                                                    \
        __builtin_amdgcn_global_load_lds(                                            \
            (const __attribute__((address_space(1))) void*)(gs + q * 16 * C),        \
            (__attribute__((address_space(3))) void*)(lb + q * 512), 16, 0, 0);      \
      asm volatile("s_waitcnt vmcnt(8)" ::: "memory");                               \
    } else {                                                                         \
      asm volatile("s_waitcnt vmcnt(0)" ::: "memory");                               \
    }                                                                                \
    __builtin_amdgcn_s_barrier();                                                    \
    asm volatile("" ::: "memory");                                                   \
    const u16* sb = smem_u16 + (CUR) * 16384;                                        \
    s16x8 ah[4], al[4];                                                              \
    _Pragma("unroll")                                                                \
    for (int rt = 0; rt < 4; ++rt) {                                                 \
      int ro = (wr + rt * 16 + l15) * 32 + (l4 ^ csw) * 8;                           \
      ah[rt] = *(const s16x8*)(sb + ro);                                             \
      al[rt] = *(const s16x8*)(sb + 4096 + ro);                                      \
    }                                                                                \
    _Pragma("unroll")                                                                \
    for (int ct = 0; ct < 4; ++ct) {                                                 \
      int co = (wc + ct * 16 + l15) * 32 + (l4 ^ csw) * 8;                           \
      s16x8 bh = *(const s16x8*)(sb + 8192 + co);                                    \
      s16x8 bl = *(const s16x8*)(sb + 12288 + co);                                   \
      _Pragma("unroll")                                                              \
      for (int rt = 0; rt < 4; ++rt) {                                               \
        acc[rt][ct] = __builtin_amdgcn_mfma_f32_16x16x32_bf16(ah[rt], bh, acc[rt][ct], 0, 0, 0); \
        acc[rt][ct] = __builtin_amdgcn_mfma_f32_16x16x32_bf16(ah[rt], bl, acc[rt][ct], 0, 0, 0); \
        acc[rt][ct] = __builtin_amdgcn_mfma_f32_16x16x32_bf16(al[rt], bh, acc[rt][ct], 0, 0, 0); \
      }                                                                              \
    }                                                                                \
    asm volatile("" ::: "memory");                                                   \
    __builtin_amdgcn_s_barrier();                                                    \
    asm volatile("" ::: "memory");                                                   \
  }

  for (int ks = 0; ks < 16; ks += 2) {
    KSTEP(0, 1, (ks + 1) * 32, true)
    KSTEP(1, 0, (ks + 2) * 32, (ks + 2 < 16))
  }
#undef KSTEP

  const float SQC = 22.627416997969522f;
  float sqi[4][4], sqj[4];
#pragma unroll
  for (int rt = 0; rt < 4; ++rt)
#pragma unroll
    for (int r = 0; r < 4; ++r) sqi[rt][r] = sqb[i0 + wr + rt * 16 + l4 * 4 + r];
#pragma unroll
  for (int ct = 0; ct < 4; ++ct) sqj[ct] = sqb[j0 + wc + ct * 16 + l15];

#pragma unroll
  for (int rt = 0; rt < 4; ++rt)
#pragma unroll
    for (int ct = 0; ct < 4; ++ct)
#pragma unroll
      for (int r = 0; r < 4; ++r) {
        float d2 = fmaxf(sqi[rt][r] + sqj[ct] - 2.0f * acc[rt][ct][r], 0.0f);
        acc[rt][ct][r] = sqrtf(d2) / SQC;
      }

  // ---- epilogue: per-wave LDS transpose (32-col passes):
  //  (a) coalesced float4 direct + mirror dist writes
  //  (b) per-row 5-NN partials
  constexpr int TSTR = 77;   // odd dword stride: column scans are conflict-free
  float* sT = (float*)smem + w * (32 * TSTR);

  float t5A[5] = {FLT_MAX, FLT_MAX, FLT_MAX, FLT_MAX, FLT_MAX};
  float mxA = 0.f;

#pragma unroll
  for (int p = 0; p < 2; ++p) {
#pragma unroll
    for (int cth = 0; cth < 2; ++cth) {
      int ct = p * 2 + cth;
      int cl = cth * 16 + l15;
#pragma unroll
      for (int rt = 0; rt < 4; ++rt)
#pragma unroll
        for (int r = 0; r < 4; ++r)
          sT[cl * TSTR + rt * 16 + l4 * 4 + r] = acc[rt][ct][r];
    }
    // direct write
    {
      int g4 = lane & 7, rbase = lane >> 3;
#pragma unroll
      for (int it = 0; it < 8; ++it) {
        int rl = it * 8 + rbase;
        float4 v = make_float4(sT[(4 * g4 + 0) * TSTR + rl],
                               sT[(4 * g4 + 1) * TSTR + rl],
                               sT[(4 * g4 + 2) * TSTR + rl],
                               sT[(4 * g4 + 3) * TSTR + rl]);
        *(float4*)(dist + (size_t)(i0 + wr + rl) * N + j0 + wc + p * 32 + 4 * g4) = v;
      }
    }
    // mirror write (scalar LDS reads: TSTR=77 breaks float4 alignment, and
    // the scalar pattern is <=2-way on banks)
    if (do_mirror) {
      int cg = lane >> 4, rq = lane & 15;
#pragma unroll
      for (int cc = 0; cc < 8; ++cc) {
        int c = cc * 4 + cg;
        float4 v;
        v.x = sT[c * TSTR + rq * 4 + 0];
        v.y = sT[c * TSTR + rq * 4 + 1];
        v.z = sT[c * TSTR + rq * 4 + 2];
        v.w = sT[c * TSTR + rq * 4 + 3];
        *(float4*)(dist + (size_t)(j0 + wc + p * 32 + c) * N + i0 + wr + rq * 4) = v;
      }
    }
    // (b1) A-side partial scan
    for (int c = 0; c < 32; ++c) {
      float v = sT[c * TSTR + lane];
      mxA = fmaxf(mxA, v);
      ins5b(t5A, v);
    }
    // (b2) mirror-side partials
    if (do_mirror) {
      int cl = lane & 31, half = lane >> 5;
      float t5B[5] = {FLT_MAX, FLT_MAX, FLT_MAX, FLT_MAX, FLT_MAX};
      float mxB = 0.f;
      for (int k = 0; k < 32; ++k) {
        float v = sT[cl * TSTR + half * 32 + k];
        mxB = fmaxf(mxB, v);
        ins5b(t5B, v);
      }
      mxB = fmaxf(mxB, __shfl_xor(mxB, 32, 64));
      float o0 = __shfl_xor(t5B[0], 32, 64);
      float o1 = __shfl_xor(t5B[1], 32, 64);
      float o2 = __shfl_xor(t5B[2], 32, 64);
      float o3 = __shfl_xor(t5B[3], 32, 64);
      float o4 = __shfl_xor(t5B[4], 32, 64);
      ins5b(t5B, o0); ins5b(t5B, o1); ins5b(t5B, o2); ins5b(t5B, o3); ins5b(t5B, o4);
      if (half == 0) {
        int rowB = j0 + wc + p * 32 + cl;
        int slotB = ti * 2 + (wr >> 6);
        float* dst = part5 + (((size_t)bl * 48 + slotB) * 6) * N + rowB;
        dst[0] = t5B[0]; dst[(size_t)N] = t5B[1]; dst[2 * (size_t)N] = t5B[2];
        dst[3 * (size_t)N] = t5B[3]; dst[4 * (size_t)N] = t5B[4]; dst[5 * (size_t)N] = mxB;
      }
    }
  }
  {
    int rowA = i0 + wr + lane;
    int slotA = tj * 2 + (wc >> 6);
    float* dst = part5 + (((size_t)bl * 48 + slotA) * 6) * N + rowA;
    dst[0] = t5A[0]; dst[(size_t)N] = t5A[1]; dst[2 * (size_t)N] = t5A[2];
    dst[3 * (size_t)N] = t5A[3]; dst[4 * (size_t)N] = t5A[4]; dst[5 * (size_t)N] = mxA;
  }
}

// ---------------- density from 48-slot partials (widened: 256 threads =
// 64 rows x 4 slot-groups of 12, merged via LDS; 4x more blocks than the
// old 1-thread-per-row version which launched only 24 blocks) ----------------
__global__ __launch_bounds__(256) void k_dens(const float* __restrict__ part5,
                                              float* __restrict__ density,
                                              float* __restrict__ distmax, int b0) {
  __shared__ float red[4][64][6];
  int tid = threadIdx.x;
  int rr = tid & 63, sg = tid >> 6;          // row-in-block, slot-group
  int row0 = blockIdx.x * 64;                // over nb*N rows, 64 per block
  int bl = row0 / N, r = (row0 % N) + rr;
  int b = b0 + bl;
  const float* base = part5 + (size_t)bl * 48 * 6 * N + r;
  float t5[5] = {FLT_MAX, FLT_MAX, FLT_MAX, FLT_MAX, FLT_MAX};
  float mx = 0.f;
  for (int s = sg * 12; s < sg * 12 + 12; ++s) {
    const float* sp = base + (size_t)s * 6 * N;
    ins5b(t5, sp[0]);
    ins5b(t5, sp[(size_t)N]);
    ins5b(t5, sp[2 * (size_t)N]);
    ins5b(t5, sp[3 * (size_t)N]);
    ins5b(t5, sp[4 * (size_t)N]);
    mx = fmaxf(mx, sp[5 * (size_t)N]);
  }
  red[sg][rr][0] = t5[0]; red[sg][rr][1] = t5[1]; red[sg][rr][2] = t5[2];
  red[sg][rr][3] = t5[3]; red[sg][rr][4] = t5[4]; red[sg][rr][5] = mx;
  __syncthreads();
  if (sg == 0) {
#pragma unroll
    for (int g = 1; g < 4; ++g) {
      ins5b(t5, red[g][rr][0]);
      ins5b(t5, red[g][rr][1]);
      ins5b(t5, red[g][rr][2]);
      ins5b(t5, red[g][rr][3]);
      ins5b(t5, red[g][rr][4]);
      mx = fmaxf(mx, red[g][rr][5]);
    }
    float sum = t5[0] * t5[0] + t5[1] * t5[1] + t5[2] * t5[2] + t5[3] * t5[3] + t5[4] * t5[4];
    density[b * N + r] = expf(-(sum / 5.0f)) + jax_uniform_bn(b * N + r) * 1e-6f;
    // fused distmax: wave-reduce then one int-atomicMax (dist >= 0 so
    // positive-float bit order == int order). Init done in k_prep.
#pragma unroll
    for (int m = 1; m < 64; m <<= 1) mx = fmaxf(mx, __shfl_xor(mx, m, 64));
    if (rr == 0) atomicMax((int*)(distmax + b), __float_as_int(mx));
  }
}

// ---------------- masked min -> score (4 rows per wave, 16 per block) ----------------
__global__ __launch_bounds__(256) void k_maskmin(const float* __restrict__ distbuf,
                                                 const float* __restrict__ density,
                                                 const float* __restrict__ distmax,
                                                 float* __restrict__ score, int b0) {
  __shared__ float sd[N];
  int tid = threadIdx.x;
  int wv = tid >> 6, lane = tid & 63;
  int bl = blockIdx.y, b = b0 + bl;
  const float* db = density + (size_t)b * N;
  for (int j = tid * 4; j < N; j += 1024) *(float4*)(sd + j) = *(const float4*)(db + j);
  __syncthreads();
  int i0r = blockIdx.x * 16 + wv * 4;
  float dmax = distmax[b];
  const float* row0 = distbuf + ((size_t)bl * N + i0r) * N;
  float di0 = sd[i0r], di1 = sd[i0r + 1], di2 = sd[i0r + 2], di3 = sd[i0r + 3];
  float mn0 = dmax, mn1 = dmax, mn2 = dmax, mn3 = dmax;
#pragma unroll 2
  for (int it = 0; it < N / 256; ++it) {
    int j = it * 256 + lane * 4;
    float4 d  = *(const float4*)(sd + j);
    float4 v0 = *(const float4*)(row0 + j);
    float4 v1 = *(const float4*)(row0 + (size_t)N + j);
    float4 v2 = *(const float4*)(row0 + 2 * (size_t)N + j);
    float4 v3 = *(const float4*)(row0 + 3 * (size_t)N + j);
    mn0 = fminf(mn0, (d.x > di0) ? v0.x : dmax);
    mn0 = fminf(mn0, (d.y > di0) ? v0.y : dmax);
    mn0 = fminf(mn0, (d.z > di0) ? v0.z : dmax);
    mn0 = fminf(mn0, (d.w > di0) ? v0.w : dmax);
    mn1 = fminf(mn1, (d.x > di1) ? v1.x : dmax);
    mn1 = fminf(mn1, (d.y > di1) ? v1.y : dmax);
    mn1 = fminf(mn1, (d.z > di1) ? v1.z : dmax);
    mn1 = fminf(mn1, (d.w > di1) ? v1.w : dmax);
    mn2 = fminf(mn2, (d.x > di2) ? v2.x : dmax);
    mn2 = fminf(mn2, (d.y > di2) ? v2.y : dmax);
    mn2 = fminf(mn2, (d.z > di2) ? v2.z : dmax);
    mn2 = fminf(mn2, (d.w > di2) ? v2.w : dmax);
    mn3 = fminf(mn3, (d.x > di3) ? v3.x : dmax);
    mn3 = fminf(mn3, (d.y > di3) ? v3.y : dmax);
    mn3 = fminf(mn3, (d.z > di3) ? v3.z : dmax);
    mn3 = fminf(mn3, (d.w > di3) ? v3.w : dmax);
  }
#pragma unroll
  for (int m = 1; m < 64; m <<= 1) {
    mn0 = fminf(mn0, __shfl_xor(mn0, m, 64));
    mn1 = fminf(mn1, __shfl_xor(mn1, m, 64));
    mn2 = fminf(mn2, __shfl_xor(mn2, m, 64));
    mn3 = fminf(mn3, __shfl_xor(mn3, m, 64));
  }
  if (lane == 0) {
    score[b * N + i0r]     = mn0 * di0;
    score[b * N + i0r + 1] = mn1 * di1;
    score[b * N + i0r + 2] = mn2 * di2;
    score[b * N + i0r + 3] = mn3 * di3;
  }
}

// ---------------- counting-rank top-CL (4 rows per wave, 16 per block) ----------------
__global__ __launch_bounds__(256) void k_rank(const float* __restrict__ score,
                                              int* __restrict__ index_down,
                                              int* __restrict__ rank, int b0) {
  __shared__ float ssc[N];
  int tid = threadIdx.x;
  int wv = tid >> 6, lane = tid & 63;
  int b = b0 + blockIdx.y;
  const float* sb = score + (size_t)b * N;
  for (int j = tid * 4; j < N; j += 1024) *(float4*)(ssc + j) = *(const float4*)(sb + j);
  __syncthreads();
  int i0r = blockIdx.x * 16 + wv * 4;
  float s0 = ssc[i0r], s1 = ssc[i0r + 1], s2 = ssc[i0r + 2], s3 = ssc[i0r + 3];
  int c0 = 0, c1 = 0, c2 = 0, c3 = 0;
#pragma unroll 2
  for (int it = 0; it < N / 256; ++it) {
    int j = it * 256 + lane * 4;
    float4 v = *(const float4*)(ssc + j);
    c0 += (v.x > s0) || (v.x == s0 && (j + 0) < i0r);
    c0 += (v.y > s0) || (v.y == s0 && (j + 1) < i0r);
    c0 += (v.z > s0) || (v.z == s0 && (j + 2) < i0r);
    c0 += (v.w > s0) || (v.w == s0 && (j + 3) < i0r);
    c1 += (v.x > s1) || (v.x == s1 && (j + 0) < i0r + 1);
    c1 += (v.y > s1) || (v.y == s1 && (j + 1) < i0r + 1);
    c1 += (v.z > s1) || (v.z == s1 && (j + 2) < i0r + 1);
    c1 += (v.w > s1) || (v.w == s1 && (j + 3) < i0r + 1);
    c2 += (v.x > s2) || (v.x == s2 && (j + 0) < i0r + 2);
    c2 += (v.y > s2) || (v.y == s2 && (j + 1) < i0r + 2);
    c2 += (v.z > s2) || (v.z == s2 && (j + 2) < i0r + 2);
    c2 += (v.w > s2) || (v.w == s2 && (j + 3) < i0r + 2);
    c3 += (v.x > s3) || (v.x == s3 && (j + 0) < i0r + 3);
    c3 += (v.y > s3) || (v.y == s3 && (j + 1) < i0r + 3);
    c3 += (v.z > s3) || (v.z == s3 && (j + 2) < i0r + 3);
    c3 += (v.w > s3) || (v.w == s3 && (j + 3) < i0r + 3);
  }
#pragma unroll
  for (int m = 1; m < 64; m <<= 1) {
    c0 += __shfl_xor(c0, m, 64);
    c1 += __shfl_xor(c1, m, 64);
    c2 += __shfl_xor(c2, m, 64);
    c3 += __shfl_xor(c3, m, 64);
  }
  if (lane == 0) {
    rank[b * N + i0r]     = (c0 < CL) ? c0 : -1;
    rank[b * N + i0r + 1] = (c1 < CL) ? c1 : -1;
    rank[b * N + i0r + 2] = (c2 < CL) ? c2 : -1;
    rank[b * N + i0r + 3] = (c3 < CL) ? c3 : -1;
    if (c0 < CL) index_down[b * CL + c0] = i0r;
    if (c1 < CL) index_down[b * CL + c1] = i0r + 1;
    if (c2 < CL) index_down[b * CL + c2] = i0r + 2;
    if (c3 < CL) index_down[b * CL + c3] = i0r + 3;
  }
}

// ---------------- assignment: chunked center rows + packed atomicMin ----------------
__global__ __launch_bounds__(256) void k_assign_part(const float* __restrict__ distbuf,
                                                     const int* __restrict__ index_down,
                                                     unsigned long long* __restrict__ packed, int b0) {
  constexpr int RCH = CL / 8;  // 96
  __shared__ int sid[RCH];
  int bl = blockIdx.z, b = b0 + bl;
  int r0 = blockIdx.y * RCH;
  int tid = threadIdx.x;
  for (int r = tid; r < RCH; r += 256) sid[r] = index_down[b * CL + r0 + r];
  __syncthreads();
  int j = blockIdx.x * 256 + tid;
  const float* base = distbuf + (size_t)bl * N * N;
  float best = FLT_MAX; int bestr = 0;
#pragma unroll 8
  for (int r = 0; r < RCH; ++r) {
    float d = base[(size_t)sid[r] * N + j];
    if (d < best) { best = d; bestr = r0 + r; }
  }
  unsigned long long key = ((unsigned long long)__float_as_uint(best) << 32) | (unsigned)bestr;
  atomicMin(&packed[b * N + j], key);
}

__global__ void k_assign_fin2(const unsigned long long* __restrict__ packed,
                              const int* __restrict__ rank,
                              int* __restrict__ idx_cluster, int* __restrict__ counts) {
  int g = blockIdx.x * 256 + threadIdx.x;
  int b = g / N;
  int r = rank[g];
  int cl = (r >= 0) ? r : (int)(unsigned)(packed[g] & 0xffffffffull);
  idx_cluster[g] = cl;
  atomicAdd(&counts[b * CL + cl], 1);
}

// ---------------- merge ----------------
__global__ __launch_bounds__(1024) void k_scan(const int* __restrict__ counts,
                                               int* __restrict__ offsets, int* __restrict__ cursor) {
  constexpr int T = B * CL;
  __shared__ int sm[T];
  int tid = threadIdx.x;
  for (int p = tid; p < T; p += 1024) sm[p] = counts[p];
  __syncthreads();
  for (int off = 1; off < T; off <<= 1) {
    int v[3]; int n = 0;
    for (int p = tid; p < T; p += 1024) { v[n++] = (p >= off) ? sm[p - off] : 0; }
    __syncthreads();
    n = 0;
    for (int p = tid; p < T; p += 1024) { sm[p] += v[n++]; }
    __syncthreads();
  }
  for (int p = tid; p < T; p += 1024) {
    int e = sm[p] - counts[p];
    offsets[p] = e; cursor[p] = e;
  }
}

__global__ void k_fill(const int* __restrict__ idx_cluster, int* __restrict__ cursor,
                       int* __restrict__ members) {
  int g = blockIdx.x * 256 + threadIdx.x;
  int b = g / N, i = g % N;
  int seg = b * CL + idx_cluster[g];
  int pos = atomicAdd(&cursor[seg], 1);
  members[pos] = i;
}

__global__ __launch_bounds__(128) void k_gather(const float* __restrict__ x, const int* __restrict__ members,
                                                const int* __restrict__ offsets, const int* __restrict__ counts,
                                                float* __restrict__ out0) {
  int seg = blockIdx.x;
  int b = seg / CL;
  int cnt = counts[seg], off = offsets[seg];
  float nw = 1.0f / ((float)cnt + 1e-6f);
  int c = threadIdx.x * 4;
  const float* xb = x + (size_t)b * N * C;
  float4 acc = make_float4(0.f, 0.f, 0.f, 0.f);
  for (int m = 0; m < cnt; ++m) {
    int tok = members[off + m];
    float4 v = *(const float4*)(xb + (size_t)tok * C + c);
    acc.x += v.x * nw; acc.y += v.y * nw; acc.z += v.z * nw; acc.w += v.w * nw;
  }
  *(float4*)(out0 + (size_t)seg * C + c) = acc;
}

__global__ void k_final(const float* __restrict__ agg_weight, const int* __restrict__ idx_token,
                        const int* __restrict__ idx_cluster, const int* __restrict__ counts,
                        float* __restrict__ out1, float* __restrict__ out2, float* __restrict__ out3) {
  int g = blockIdx.x * 256 + threadIdx.x;
  int b = g / N;
  int it = idx_token[g];
  int clt = idx_cluster[b * N + it];
  float nwt = 1.0f / ((float)counts[b * CL + clt] + 1e-6f);
  out1[g] = agg_weight[g] * nwt;
  out2[g] = (float)clt;
  out3[g] = (float)idx_cluster[g];
}

// ---------------- launch ----------------
extern "C" void kernel_launch(void* const* d_in, const int* in_sizes, int n_in,
                              void* d_out, int out_size, void* d_ws, size_t ws_size,
                              hipStream_t stream) {
  const float* x          = (const float*)d_in[0];
  const int*   idx_token  = (const int*)d_in[1];
  const float* agg_weight = (const float*)d_in[2];

  float* out0 = (float*)d_out;
  float* out1 = out0 + (size_t)B * CL * C;
  float* out2 = out1 + (size_t)B * N;
  float* out3 = out2 + (size_t)B * N;

  char* w = (char*)d_ws;
  auto carve = [&](size_t bytes) { char* p = w; w += (bytes + 255) & ~(size_t)255; return p; };
  float*    sq         = (float*)carve((size_t)B * N * 4);
  float*    density    = (float*)carve((size_t)B * N * 4);
  float*    score      = (float*)carve((size_t)B * N * 4);
  float*    distmax    = (float*)carve((size_t)B * 4);
  int*      index_down = (int*)carve((size_t)B * CL * 4);
  int*      rank       = (int*)carve((size_t)B * N * 4);
  int*      idx_clus   = (int*)carve((size_t)B * N * 4);
  int*      counts     = (int*)carve((size_t)B * CL * 4);
  int*      offsets    = (int*)carve((size_t)B * CL * 4);
  int*      cursor     = (int*)carve((size_t)B * CL * 4);
  int*      members    = (int*)carve((size_t)B * N * 4);
  unsigned long long* packed = (unsigned long long*)carve((size_t)B * N * 8);
  u16*      xhi        = (u16*)carve((size_t)B * N * C * 2);
  u16*      xlo        = (u16*)carve((size_t)B * N * C * 2);
  float*    part5      = (float*)carve((size_t)B * 48 * 6 * N * 4);
  size_t used = (size_t)(w - (char*)d_ws);
  size_t per  = (size_t)N * N * 4;
  int nb_max = (ws_size > used) ? (int)((ws_size - used) / per) : 0;
  if (nb_max < 1) nb_max = 1;
  if (nb_max > B) nb_max = B;
  float* distbuf = (float*)w;

  k_prep<<<B * N, 64, 0, stream>>>(x, sq, xhi, xlo, counts, packed, distmax);

  for (int b0 = 0; b0 < B; b0 += nb_max) {
    int nb = (B - b0 < nb_max) ? (B - b0) : nb_max;
    k_distm<<<dim3(NTILE3, nb), 256, 0, stream>>>(xhi, xlo, sq, distbuf, part5, b0);
    k_dens<<<(nb * N) / 64, 256, 0, stream>>>(part5, density, distmax, b0);
    k_maskmin<<<dim3(N / 16, nb), 256, 0, stream>>>(distbuf, density, distmax, score, b0);
    k_rank<<<dim3(N / 16, nb), 256, 0, stream>>>(score, index_down, rank, b0);
    k_assign_part<<<dim3(N / 256, 8, nb), 256, 0, stream>>>(distbuf, index_down, packed, b0);
  }

  k_assign_fin2<<<(B * N) / 256, 256, 0, stream>>>(packed, rank, idx_clus, counts);
  k_scan<<<1, 1024, 0, stream>>>(counts, offsets, cursor);
  k_fill<<<(B * N) / 256, 256, 0, stream>>>(idx_clus, cursor, members);
  k_gather<<<B * CL, 128, 0, stream>>>(x, members, offsets, counts, out0);
  k_final<<<(B * N) / 256, 256, 0, stream>>>(agg_weight, idx_token, idx_clus, counts, out1, out2, out3);
}